// Round 4
// baseline (492.034 us; speedup 1.0000x reference)
//
#include <hip/hip_runtime.h>
#include <hip/hip_bf16.h>
#include <stdint.h>

#define NN 8192
#define FD 256
#define NEG_BIG (-1000000000.0f)
#define SLOPE 0.2f

typedef float f32x4_t __attribute__((ext_vector_type(4)));
typedef __bf16 bf16x8_t __attribute__((ext_vector_type(8)));
typedef unsigned short u16x8_t __attribute__((ext_vector_type(8)));

__device__ __forceinline__ unsigned short f2bf(float x) {
  unsigned int u = __builtin_bit_cast(unsigned int, x);
  u += 0x7FFFu + ((u >> 16) & 1u);   // RNE
  return (unsigned short)(u >> 16);
}

__device__ __forceinline__ float redsum16(float v) {
#pragma unroll
  for (int m = 1; m < 16; m <<= 1) v += __shfl_xor(v, m, 64);
  return v;
}

// ---------------- kernel 0: c1/c2[k] = sum_f W[f][k]*a{1,2}[f] ----------------
__global__ void gat_cvec(const float* __restrict__ W, const float* __restrict__ a,
                         float* __restrict__ c1, float* __restrict__ c2) {
  const int k = threadIdx.x;
  float acc1 = 0.f, acc2 = 0.f;
#pragma unroll 8
  for (int f = 0; f < FD; ++f) {
    float w = W[f * FD + k];
    acc1 = fmaf(w, a[f], acc1);
    acc2 = fmaf(w, a[FD + f], acc2);
  }
  c1[k] = acc1;
  c2[k] = acc2;
}

// ---------------- kernel 1: s1/s2[i] = h[i] . c1/c2  (one wave per row) ------
__global__ void gat_svec(const float* __restrict__ h, const float* __restrict__ c1,
                         const float* __restrict__ c2, float* __restrict__ s1,
                         float* __restrict__ s2) {
  const int i = blockIdx.x * 4 + (threadIdx.x >> 6);
  const int lane = threadIdx.x & 63;
  float4 hv = *(const float4*)(h + (size_t)i * FD + lane * 4);
  float4 u = *(const float4*)(c1 + lane * 4);
  float4 v = *(const float4*)(c2 + lane * 4);
  float d1 = hv.x * u.x + hv.y * u.y + hv.z * u.z + hv.w * u.w;
  float d2 = hv.x * v.x + hv.y * v.y + hv.z * v.z + hv.w * v.w;
#pragma unroll
  for (int m = 1; m < 64; m <<= 1) {
    d1 += __shfl_xor(d1, m, 64);
    d2 += __shfl_xor(d2, m, 64);
  }
  if (lane == 0) {
    s1[i] = d1;
    s2[i] = d2;
  }
}

// ---------------- kernel 2: WhT[f][i] = bf16( (h @ W^T)[i][f] ), fp32 compute -
__launch_bounds__(256)
__global__ void gat_wht(const float* __restrict__ h, const float* __restrict__ W,
                        unsigned short* __restrict__ whT) {
  __shared__ __align__(16) float hT[64][64];  // [k][i]
  __shared__ __align__(16) float wT[64][64];  // [k][f]
  const int t = threadIdx.x;
  const int i0 = blockIdx.x * 64;
  const int f0 = blockIdx.y * 64;
  const int r = t & 63;
  const int kq = t >> 6;
  const int ty = t >> 4;  // row group (i)
  const int tx = t & 15;  // col group (f)
  float acc[4][4] = {};
  for (int k0 = 0; k0 < FD; k0 += 64) {
#pragma unroll
    for (int kk = 0; kk < 16; kk += 4) {
      float4 v = *(const float4*)(h + (size_t)(i0 + r) * FD + k0 + kq * 16 + kk);
      hT[kq * 16 + kk + 0][r] = v.x;
      hT[kq * 16 + kk + 1][r] = v.y;
      hT[kq * 16 + kk + 2][r] = v.z;
      hT[kq * 16 + kk + 3][r] = v.w;
      float4 u = *(const float4*)(W + (size_t)(f0 + r) * FD + k0 + kq * 16 + kk);
      wT[kq * 16 + kk + 0][r] = u.x;
      wT[kq * 16 + kk + 1][r] = u.y;
      wT[kq * 16 + kk + 2][r] = u.z;
      wT[kq * 16 + kk + 3][r] = u.w;
    }
    __syncthreads();
#pragma unroll 8
    for (int kk = 0; kk < 64; ++kk) {
      float4 av = *(const float4*)&hT[kk][ty * 4];
      float4 bv = *(const float4*)&wT[kk][tx * 4];
      acc[0][0] = fmaf(av.x, bv.x, acc[0][0]);
      acc[0][1] = fmaf(av.x, bv.y, acc[0][1]);
      acc[0][2] = fmaf(av.x, bv.z, acc[0][2]);
      acc[0][3] = fmaf(av.x, bv.w, acc[0][3]);
      acc[1][0] = fmaf(av.y, bv.x, acc[1][0]);
      acc[1][1] = fmaf(av.y, bv.y, acc[1][1]);
      acc[1][2] = fmaf(av.y, bv.z, acc[1][2]);
      acc[1][3] = fmaf(av.y, bv.w, acc[1][3]);
      acc[2][0] = fmaf(av.z, bv.x, acc[2][0]);
      acc[2][1] = fmaf(av.z, bv.y, acc[2][1]);
      acc[2][2] = fmaf(av.z, bv.z, acc[2][2]);
      acc[2][3] = fmaf(av.z, bv.w, acc[2][3]);
      acc[3][0] = fmaf(av.w, bv.x, acc[3][0]);
      acc[3][1] = fmaf(av.w, bv.y, acc[3][1]);
      acc[3][2] = fmaf(av.w, bv.z, acc[3][2]);
      acc[3][3] = fmaf(av.w, bv.w, acc[3][3]);
    }
    __syncthreads();
  }
#pragma unroll
  for (int j = 0; j < 4; ++j) {
    ushort4 o;
    o.x = f2bf(acc[0][j]);
    o.y = f2bf(acc[1][j]);
    o.z = f2bf(acc[2][j]);
    o.w = f2bf(acc[3][j]);
    *(ushort4*)(whT + (size_t)(f0 + tx * 4 + j) * NN + i0 + ty * 4) = o;
  }
}

// ---------------- kernel 3: fused masked attention, BN=256 wide tiles --------
// grid (256, NSPLIT) x 512 thr; BM=32 rows/block, BN=256 cols/iter.
// Each adj row is read 1 KB-contiguous per iteration (DRAM row-friendly);
// adj/s2 for tile t+1 prefetched at t (full-iteration leadtime). P staged in
// parity-double-buffered LDS; ONE lgkm-only raw barrier per iteration.
// Wave w owns f-slice [w*32, w*32+32); B-frags global->reg (whT L2-resident).
__launch_bounds__(512, 8)
__global__ void gat_attn(const int* __restrict__ adj, const float* __restrict__ s1g,
                         const float* __restrict__ s2g,
                         const unsigned short* __restrict__ whT,
                         float* __restrict__ accP, float* __restrict__ lP,
                         int jcols) {
  __shared__ __align__(16) unsigned short p_s[2][32 * 256];  // 2 x 16 KB, swizzled

  const int tid = threadIdx.x;
  const int lane = tid & 63;
  const int w = tid >> 6;
  const int i0 = blockIdx.x * 32;
  const int jbase = blockIdx.y * jcols;
  const int ntiles = jcols >> 8;

  const int rE = tid >> 4;         // 0..31 row within block
  const int cb = (tid & 15) * 16;  // col base within 256-tile

  const float s1r = s1g[i0 + rE];
  float l_r = 0.0f;

  f32x4_t acc[2][2];
  const f32x4_t zero4 = {0.f, 0.f, 0.f, 0.f};
#pragma unroll
  for (int r = 0; r < 2; ++r)
#pragma unroll
    for (int ct = 0; ct < 2; ++ct) acc[r][ct] = zero4;

  const int* adj_row = adj + (size_t)(i0 + rE) * NN + jbase + cb;
  const float* s2_row = s2g + jbase + cb;
  // B-frag bases: row = w*32 + ct*16 + (lane&15), k-offset (lane>>4)*8
  const unsigned short* bp0 =
      whT + (size_t)(w * 32 + (lane & 15)) * NN + jbase + (lane >> 4) * 8;
  const unsigned short* bp1 = bp0 + (size_t)16 * NN;

  const int swzE = rE & 7;        // E-phase write swizzle
  const int swzA = lane & 7;      // M-phase A-read swizzle ((arow&7), both r)
  const int ch0 = ((tid & 15) * 2) ^ swzE;
  const int ch1 = ((tid & 15) * 2 + 1) ^ swzE;

  // ---- prologue: tile 0 adj/s2 ----
  int4 a0 = *(const int4*)(adj_row + 0);
  int4 a1 = *(const int4*)(adj_row + 4);
  int4 a2 = *(const int4*)(adj_row + 8);
  int4 a3 = *(const int4*)(adj_row + 12);
  float4 s0 = *(const float4*)(s2_row + 0);
  float4 s1v = *(const float4*)(s2_row + 4);
  float4 s2v = *(const float4*)(s2_row + 8);
  float4 s3 = *(const float4*)(s2_row + 12);

  for (int t = 0; t < ntiles; ++t) {
    const int j0 = t << 8;
    unsigned short* ps = p_s[t & 1];

    // ---- B-frags kc=0..3 for THIS tile (L2 latency hides under E) ----
    bf16x8_t bA0 = *(const bf16x8_t*)(bp0 + j0 + 0 * 32);
    bf16x8_t bA1 = *(const bf16x8_t*)(bp0 + j0 + 1 * 32);
    bf16x8_t bA2 = *(const bf16x8_t*)(bp0 + j0 + 2 * 32);
    bf16x8_t bA3 = *(const bf16x8_t*)(bp0 + j0 + 3 * 32);
    bf16x8_t bB0 = *(const bf16x8_t*)(bp1 + j0 + 0 * 32);
    bf16x8_t bB1 = *(const bf16x8_t*)(bp1 + j0 + 1 * 32);
    bf16x8_t bB2 = *(const bf16x8_t*)(bp1 + j0 + 2 * 32);
    bf16x8_t bB3 = *(const bf16x8_t*)(bp1 + j0 + 3 * 32);

    // ---- Phase E: 16 cols/thread, exp (no max; e bounded ~6) ----
    float pv[16];
    {
      const int am[16] = {a0.x, a0.y, a0.z, a0.w, a1.x, a1.y, a1.z, a1.w,
                          a2.x, a2.y, a2.z, a2.w, a3.x, a3.y, a3.z, a3.w};
      const float sv[16] = {s0.x, s0.y, s0.z, s0.w, s1v.x, s1v.y, s1v.z, s1v.w,
                            s2v.x, s2v.y, s2v.z, s2v.w, s3.x, s3.y, s3.z, s3.w};
#pragma unroll
      for (int c = 0; c < 16; ++c) {
        float e = s1r + sv[c];
        e = fmaxf(e, SLOPE * e);
        pv[c] = am[c] != 0 ? __expf(e) : 0.f;
        l_r += pv[c];
      }
    }
    {
      u16x8_t w0, w1;
#pragma unroll
      for (int c = 0; c < 8; ++c) {
        w0[c] = f2bf(pv[c]);
        w1[c] = f2bf(pv[c + 8]);
      }
      *(u16x8_t*)&ps[rE * 256 + ch0 * 8] = w0;
      *(u16x8_t*)&ps[rE * 256 + ch1 * 8] = w1;
    }

    // ---- prefetch next tile's adj/s2 (full-iteration leadtime) ----
    const int jn = (t + 1 < ntiles) ? j0 + 256 : j0;
    a0 = *(const int4*)(adj_row + jn + 0);
    a1 = *(const int4*)(adj_row + jn + 4);
    a2 = *(const int4*)(adj_row + jn + 8);
    a3 = *(const int4*)(adj_row + jn + 12);
    s0 = *(const float4*)(s2_row + jn + 0);
    s1v = *(const float4*)(s2_row + jn + 4);
    s2v = *(const float4*)(s2_row + jn + 8);
    s3 = *(const float4*)(s2_row + jn + 12);

    // ---- single raw barrier: drain LDS writes only, NOT vmem ----
    asm volatile("s_waitcnt lgkmcnt(0)" ::: "memory");
    __builtin_amdgcn_s_barrier();
    __builtin_amdgcn_sched_barrier(0);

    // ---- B-frags kc=4..7 (consumed ~300cy later; L2-hit) ----
    bf16x8_t bA4 = *(const bf16x8_t*)(bp0 + j0 + 4 * 32);
    bf16x8_t bA5 = *(const bf16x8_t*)(bp0 + j0 + 5 * 32);
    bf16x8_t bA6 = *(const bf16x8_t*)(bp0 + j0 + 6 * 32);
    bf16x8_t bA7 = *(const bf16x8_t*)(bp0 + j0 + 7 * 32);
    bf16x8_t bB4 = *(const bf16x8_t*)(bp1 + j0 + 4 * 32);
    bf16x8_t bB5 = *(const bf16x8_t*)(bp1 + j0 + 5 * 32);
    bf16x8_t bB6 = *(const bf16x8_t*)(bp1 + j0 + 6 * 32);
    bf16x8_t bB7 = *(const bf16x8_t*)(bp1 + j0 + 7 * 32);

    // ---- Phase M: P @ Wh, K=256 = 8 kc-chunks ----
    const int arow0 = (lane & 15) * 256;
    const int arow1 = arow0 + 16 * 256;
#define GAT_MFMA_KC(kc, bA, bB)                                                   \
  {                                                                               \
    const int chk = (((kc) << 2) + (lane >> 4)) ^ swzA;                           \
    bf16x8_t af0 = *(const bf16x8_t*)&ps[arow0 + chk * 8];                        \
    bf16x8_t af1 = *(const bf16x8_t*)&ps[arow1 + chk * 8];                        \
    acc[0][0] = __builtin_amdgcn_mfma_f32_16x16x32_bf16(af0, bA, acc[0][0], 0, 0, 0); \
    acc[0][1] = __builtin_amdgcn_mfma_f32_16x16x32_bf16(af0, bB, acc[0][1], 0, 0, 0); \
    acc[1][0] = __builtin_amdgcn_mfma_f32_16x16x32_bf16(af1, bA, acc[1][0], 0, 0, 0); \
    acc[1][1] = __builtin_amdgcn_mfma_f32_16x16x32_bf16(af1, bB, acc[1][1], 0, 0, 0); \
  }
    GAT_MFMA_KC(0, bA0, bB0)
    GAT_MFMA_KC(1, bA1, bB1)
    GAT_MFMA_KC(2, bA2, bB2)
    GAT_MFMA_KC(3, bA3, bB3)
    GAT_MFMA_KC(4, bA4, bB4)
    GAT_MFMA_KC(5, bA5, bB5)
    GAT_MFMA_KC(6, bA6, bB6)
    GAT_MFMA_KC(7, bA7, bB7)
#undef GAT_MFMA_KC
  }

  // ---- write partials ----
  float lsum = redsum16(l_r);
  if ((tid & 15) == 0) lP[(size_t)blockIdx.y * NN + i0 + rE] = lsum;

  const size_t pbase = ((size_t)blockIdx.y * NN + i0) * FD;
#pragma unroll
  for (int r = 0; r < 2; ++r) {
#pragma unroll
    for (int ct = 0; ct < 2; ++ct) {
      const int col = w * 32 + ct * 16 + (lane & 15);
#pragma unroll
      for (int g = 0; g < 4; ++g) {
        const int row = r * 16 + ((lane >> 4) << 2) + g;
        accP[pbase + (size_t)row * FD + col] = acc[r][ct][g];
      }
    }
  }
}

// ---------------- kernel 4: merge partials, divide by l ----------------------
__global__ void gat_merge(const float* __restrict__ accP, const float* __restrict__ lP,
                          float* __restrict__ out, int nsplit) {
  const int i = blockIdx.x;
  const int f = threadIdx.x;
  float s = 0.f, l = 0.f;
  for (int q = 0; q < nsplit; ++q) {
    s += accP[((size_t)q * NN + i) * FD + f];
    l += lP[(size_t)q * NN + i];
  }
  out[(size_t)i * FD + f] = s / l;
}

extern "C" void kernel_launch(void* const* d_in, const int* in_sizes, int n_in,
                              void* d_out, int out_size, void* d_ws, size_t ws_size,
                              hipStream_t stream) {
  const float* h = (const float*)d_in[0];
  const int* adj = (const int*)d_in[1];
  const float* W = (const float*)d_in[2];
  const float* a = (const float*)d_in[3];
  float* out = (float*)d_out;

  char* ws = (char*)d_ws;
  unsigned short* whT = (unsigned short*)ws;          // 256*8192*2 = 4 MB
  float* s1 = (float*)(ws + 4194304);                 // 32 KB
  float* s2 = (float*)(ws + 4194304 + 32768);         // 32 KB
  float* c1 = (float*)(ws + 4194304 + 65536);         // 1 KB
  float* c2 = (float*)(ws + 4194304 + 65536 + 1024);  // 1 KB
  const size_t partOff = 5ull * 1024 * 1024;

  // choose j-split so partials fit ws (ws_size fixed -> deterministic)
  int nsplit = 4;
  {
    auto need = [&](int q) {
      return partOff + (size_t)q * ((size_t)NN * FD * 4 + (size_t)NN * 4);
    };
    if (ws_size < need(4)) nsplit = (ws_size >= need(2)) ? 2 : 1;
  }
  float* accP = (float*)(ws + partOff);
  float* lP = (float*)(ws + partOff + (size_t)nsplit * NN * FD * 4);
  const int jcols = NN / nsplit;

  gat_cvec<<<1, 256, 0, stream>>>(W, a, c1, c2);
  gat_svec<<<NN / 4, 256, 0, stream>>>(h, c1, c2, s1, s2);
  gat_wht<<<dim3(NN / 64, FD / 64), 256, 0, stream>>>(h, W, whT);
  gat_attn<<<dim3(NN / 32, nsplit), 512, 0, stream>>>(adj, s1, s2, whT, accP, lP, jcols);
  gat_merge<<<NN, FD, 0, stream>>>(accP, lP, out, nsplit);
}

// Round 5
// 349.880 us; speedup vs baseline: 1.4063x; 1.4063x over previous
//
#include <hip/hip_runtime.h>
#include <hip/hip_bf16.h>
#include <stdint.h>

#define NN 8192
#define FD 256
#define SLOPE 0.2f

typedef float f32x4_t __attribute__((ext_vector_type(4)));
typedef __bf16 bf16x8_t __attribute__((ext_vector_type(8)));
typedef unsigned short u16x8_t __attribute__((ext_vector_type(8)));

__device__ __forceinline__ unsigned short f2bf(float x) {
  unsigned int u = __builtin_bit_cast(unsigned int, x);
  u += 0x7FFFu + ((u >> 16) & 1u);  // RNE
  return (unsigned short)(u >> 16);
}

// ---------------- kernel 0: c1/c2[k] = sum_f W[f][k]*a{1,2}[f] ----------------
__global__ void gat_cvec(const float* __restrict__ W, const float* __restrict__ a,
                         float* __restrict__ c1, float* __restrict__ c2) {
  const int k = threadIdx.x;
  float acc1 = 0.f, acc2 = 0.f;
#pragma unroll 8
  for (int f = 0; f < FD; ++f) {
    float w = W[f * FD + k];
    acc1 = fmaf(w, a[f], acc1);
    acc2 = fmaf(w, a[FD + f], acc2);
  }
  c1[k] = acc1;
  c2[k] = acc2;
}

// ---------------- kernel 1: s1/s2[i] = h[i] . c1/c2  (one wave per row) ------
__global__ void gat_svec(const float* __restrict__ h, const float* __restrict__ c1,
                         const float* __restrict__ c2, float* __restrict__ s1,
                         float* __restrict__ s2) {
  const int i = blockIdx.x * 4 + (threadIdx.x >> 6);
  const int lane = threadIdx.x & 63;
  float4 hv = *(const float4*)(h + (size_t)i * FD + lane * 4);
  float4 u = *(const float4*)(c1 + lane * 4);
  float4 v = *(const float4*)(c2 + lane * 4);
  float d1 = hv.x * u.x + hv.y * u.y + hv.z * u.z + hv.w * u.w;
  float d2 = hv.x * v.x + hv.y * v.y + hv.z * v.z + hv.w * v.w;
#pragma unroll
  for (int m = 1; m < 64; m <<= 1) {
    d1 += __shfl_xor(d1, m, 64);
    d2 += __shfl_xor(d2, m, 64);
  }
  if (lane == 0) {
    s1[i] = d1;
    s2[i] = d2;
  }
}

// ---------------- kernel 2: WhT[f][i] = bf16( (h @ W^T)[i][f] ), fp32 compute -
__launch_bounds__(256)
__global__ void gat_wht(const float* __restrict__ h, const float* __restrict__ W,
                        unsigned short* __restrict__ whT) {
  __shared__ __align__(16) float hT[64][64];  // [k][i]
  __shared__ __align__(16) float wT[64][64];  // [k][f]
  const int t = threadIdx.x;
  const int i0 = blockIdx.x * 64;
  const int f0 = blockIdx.y * 64;
  const int r = t & 63;
  const int kq = t >> 6;
  const int ty = t >> 4;  // row group (i)
  const int tx = t & 15;  // col group (f)
  float acc[4][4] = {};
  for (int k0 = 0; k0 < FD; k0 += 64) {
#pragma unroll
    for (int kk = 0; kk < 16; kk += 4) {
      float4 v = *(const float4*)(h + (size_t)(i0 + r) * FD + k0 + kq * 16 + kk);
      hT[kq * 16 + kk + 0][r] = v.x;
      hT[kq * 16 + kk + 1][r] = v.y;
      hT[kq * 16 + kk + 2][r] = v.z;
      hT[kq * 16 + kk + 3][r] = v.w;
      float4 u = *(const float4*)(W + (size_t)(f0 + r) * FD + k0 + kq * 16 + kk);
      wT[kq * 16 + kk + 0][r] = u.x;
      wT[kq * 16 + kk + 1][r] = u.y;
      wT[kq * 16 + kk + 2][r] = u.z;
      wT[kq * 16 + kk + 3][r] = u.w;
    }
    __syncthreads();
#pragma unroll 8
    for (int kk = 0; kk < 64; ++kk) {
      float4 av = *(const float4*)&hT[kk][ty * 4];
      float4 bv = *(const float4*)&wT[kk][tx * 4];
      acc[0][0] = fmaf(av.x, bv.x, acc[0][0]);
      acc[0][1] = fmaf(av.x, bv.y, acc[0][1]);
      acc[0][2] = fmaf(av.x, bv.z, acc[0][2]);
      acc[0][3] = fmaf(av.x, bv.w, acc[0][3]);
      acc[1][0] = fmaf(av.y, bv.x, acc[1][0]);
      acc[1][1] = fmaf(av.y, bv.y, acc[1][1]);
      acc[1][2] = fmaf(av.y, bv.z, acc[1][2]);
      acc[1][3] = fmaf(av.y, bv.w, acc[1][3]);
      acc[2][0] = fmaf(av.z, bv.x, acc[2][0]);
      acc[2][1] = fmaf(av.z, bv.y, acc[2][1]);
      acc[2][2] = fmaf(av.z, bv.z, acc[2][2]);
      acc[2][3] = fmaf(av.z, bv.w, acc[2][3]);
      acc[3][0] = fmaf(av.w, bv.x, acc[3][0]);
      acc[3][1] = fmaf(av.w, bv.y, acc[3][1]);
      acc[3][2] = fmaf(av.w, bv.z, acc[3][2]);
      acc[3][3] = fmaf(av.w, bv.w, acc[3][3]);
    }
    __syncthreads();
  }
#pragma unroll
  for (int j = 0; j < 4; ++j) {
    ushort4 o;
    o.x = f2bf(acc[0][j]);
    o.y = f2bf(acc[1][j]);
    o.z = f2bf(acc[2][j]);
    o.w = f2bf(acc[3][j]);
    *(ushort4*)(whT + (size_t)(f0 + tx * 4 + j) * NN + i0 + ty * 4) = o;
  }
}

// ---- build one MFMA A-fragment worth of P (8 cols) directly in registers ----
__device__ __forceinline__ bf16x8_t make_afrag(float s1r, const float4& slo,
                                               const float4& shi, const int4& ml,
                                               const int4& mh, float& lsum) {
  const float sv[8] = {slo.x, slo.y, slo.z, slo.w, shi.x, shi.y, shi.z, shi.w};
  const int mm[8] = {ml.x, ml.y, ml.z, ml.w, mh.x, mh.y, mh.z, mh.w};
  u16x8_t ru;
#pragma unroll
  for (int c = 0; c < 8; ++c) {
    float e = s1r + sv[c];
    e = fmaxf(e, SLOPE * e);
    float pv = mm[c] != 0 ? __expf(e) : 0.f;
    lsum += pv;
    ru[c] = f2bf(pv);
  }
  return __builtin_bit_cast(bf16x8_t, ru);
}

// ---------------- kernel 3: barrier-free fused masked attention --------------
// One wave = 32 rows x 128 f-cols x 2048-k slice. P is computed per-lane
// directly in MFMA A-fragment layout (row=lane&15, k-group=lane>>4) -> no LDS,
// no barriers, no lockstep. Waves stream independently; 8 shared B-frags per
// 32-k chunk (whT is L2-resident per XCD). Partials accP[ks]/lP[ks] merged by
// gat_merge. Grid 512 x 256thr: block = {rs} x {2 fh} x {2 of 4 ks}.
__launch_bounds__(256, 2)
__global__ void gat_attn(const int* __restrict__ adj, const float* __restrict__ s1g,
                         const float* __restrict__ s2g,
                         const unsigned short* __restrict__ whT,
                         float* __restrict__ accP, float* __restrict__ lP) {
  const int lane = threadIdx.x & 63;
  const int w = threadIdx.x >> 6;
  const int rs = blockIdx.x >> 1;                   // 0..255 (32-row sets)
  const int ks = (blockIdx.x & 1) * 2 + (w >> 1);   // 0..3 (2048-k slices)
  const int fh = w & 1;                             // 0..1 (128-f halves)
  const int kbase = ks * 2048;
  const int f0 = fh * 128;
  const int r16 = lane & 15;
  const int kg = lane >> 4;  // k-group 0..3 (8 k each)

  const int row0 = rs * 32 + r16;
  const int* arow0 = adj + (size_t)row0 * NN + kbase + kg * 8;
  const int* arow1 = arow0 + (size_t)16 * NN;
  const float* s2p = s2g + kbase + kg * 8;
  const unsigned short* bp = whT + (size_t)(f0 + r16) * NN + kbase + kg * 8;

  const float s1r0 = s1g[row0];
  const float s1r1 = s1g[row0 + 16];

  f32x4_t acc[2][8];
  const f32x4_t zero4 = {0.f, 0.f, 0.f, 0.f};
#pragma unroll
  for (int rt = 0; rt < 2; ++rt)
#pragma unroll
    for (int ct = 0; ct < 8; ++ct) acc[rt][ct] = zero4;

  float l0 = 0.f, l1 = 0.f;

  for (int kk = 0; kk < 2048; kk += 32) {
    // masks + s2 for this lane's 8 k-slots (two 16B loads each)
    int4 m0l = *(const int4*)(arow0 + kk);
    int4 m0h = *(const int4*)(arow0 + kk + 4);
    int4 m1l = *(const int4*)(arow1 + kk);
    int4 m1h = *(const int4*)(arow1 + kk + 4);
    float4 sl = *(const float4*)(s2p + kk);
    float4 sh = *(const float4*)(s2p + kk + 4);

    bf16x8_t af0 = make_afrag(s1r0, sl, sh, m0l, m0h, l0);
    bf16x8_t af1 = make_afrag(s1r1, sl, sh, m1l, m1h, l1);

#pragma unroll
    for (int ct = 0; ct < 8; ++ct) {
      bf16x8_t b = *(const bf16x8_t*)(bp + (size_t)ct * 16 * NN + kk);
      acc[0][ct] = __builtin_amdgcn_mfma_f32_16x16x32_bf16(af0, b, acc[0][ct], 0, 0, 0);
      acc[1][ct] = __builtin_amdgcn_mfma_f32_16x16x32_bf16(af1, b, acc[1][ct], 0, 0, 0);
    }
  }

  // ---- row-sum l across the 4 k-group lanes of each row ----
  l0 += __shfl_xor(l0, 16, 64);
  l0 += __shfl_xor(l0, 32, 64);
  l1 += __shfl_xor(l1, 16, 64);
  l1 += __shfl_xor(l1, 32, 64);
  if (fh == 0 && kg == 0) {
    lP[(size_t)ks * NN + row0] = l0;
    lP[(size_t)ks * NN + row0 + 16] = l1;
  }

  // ---- write partial acc: row = rs*32 + rt*16 + kg*4 + g, col = f0+ct*16+r16
  float* ap = accP + (size_t)ks * NN * FD;
#pragma unroll
  for (int rt = 0; rt < 2; ++rt) {
#pragma unroll
    for (int ct = 0; ct < 8; ++ct) {
      const int col = f0 + ct * 16 + r16;
#pragma unroll
      for (int g = 0; g < 4; ++g) {
        const int row = rs * 32 + rt * 16 + kg * 4 + g;
        ap[(size_t)row * FD + col] = acc[rt][ct][g];
      }
    }
  }
}

// ---------------- kernel 4: merge partials, divide by l ----------------------
__global__ void gat_merge(const float* __restrict__ accP, const float* __restrict__ lP,
                          float* __restrict__ out, int nsplit) {
  const int i = blockIdx.x;
  const int f = threadIdx.x;
  float s = 0.f, l = 0.f;
  for (int q = 0; q < nsplit; ++q) {
    s += accP[((size_t)q * NN + i) * FD + f];
    l += lP[(size_t)q * NN + i];
  }
  out[(size_t)i * FD + f] = s / l;
}

extern "C" void kernel_launch(void* const* d_in, const int* in_sizes, int n_in,
                              void* d_out, int out_size, void* d_ws, size_t ws_size,
                              hipStream_t stream) {
  const float* h = (const float*)d_in[0];
  const int* adj = (const int*)d_in[1];
  const float* W = (const float*)d_in[2];
  const float* a = (const float*)d_in[3];
  float* out = (float*)d_out;

  char* ws = (char*)d_ws;
  unsigned short* whT = (unsigned short*)ws;          // 256*8192*2 = 4 MB
  float* s1 = (float*)(ws + 4194304);                 // 32 KB
  float* s2 = (float*)(ws + 4194304 + 32768);         // 32 KB
  float* c1 = (float*)(ws + 4194304 + 65536);         // 1 KB
  float* c2 = (float*)(ws + 4194304 + 65536 + 1024);  // 1 KB
  const size_t partOff = 5ull * 1024 * 1024;
  float* accP = (float*)(ws + partOff);                         // 4 x 8 MB
  float* lP = (float*)(ws + partOff + 4ull * NN * FD * 4);      // 4 x 32 KB

  gat_cvec<<<1, 256, 0, stream>>>(W, a, c1, c2);
  gat_svec<<<NN / 4, 256, 0, stream>>>(h, c1, c2, s1, s2);
  gat_wht<<<dim3(NN / 64, FD / 64), 256, 0, stream>>>(h, W, whT);
  gat_attn<<<512, 256, 0, stream>>>(adj, s1, s2, whT, accP, lP);
  gat_merge<<<NN, FD, 0, stream>>>(accP, lP, out, 4);
}

// Round 6
// 329.693 us; speedup vs baseline: 1.4924x; 1.0612x over previous
//
#include <hip/hip_runtime.h>
#include <hip/hip_bf16.h>
#include <stdint.h>

#define NN 8192
#define FD 256
#define SLOPE 0.2f

typedef float f32x4_t __attribute__((ext_vector_type(4)));
typedef __bf16 bf16x8_t __attribute__((ext_vector_type(8)));
typedef unsigned short u16x8_t __attribute__((ext_vector_type(8)));

__device__ __forceinline__ unsigned short f2bf(float x) {
  unsigned int u = __builtin_bit_cast(unsigned int, x);
  u += 0x7FFFu + ((u >> 16) & 1u);  // RNE
  return (unsigned short)(u >> 16);
}

// ---------------- kernel 0: c1/c2[k] = sum_f W[f][k]*a{1,2}[f] ----------------
__global__ void gat_cvec(const float* __restrict__ W, const float* __restrict__ a,
                         float* __restrict__ c1, float* __restrict__ c2) {
  const int k = threadIdx.x;
  float acc1 = 0.f, acc2 = 0.f;
#pragma unroll 8
  for (int f = 0; f < FD; ++f) {
    float w = W[f * FD + k];
    acc1 = fmaf(w, a[f], acc1);
    acc2 = fmaf(w, a[FD + f], acc2);
  }
  c1[k] = acc1;
  c2[k] = acc2;
}

// ---------------- kernel 1: s1/s2[i] = h[i] . c1/c2  (one wave per row) ------
__global__ void gat_svec(const float* __restrict__ h, const float* __restrict__ c1,
                         const float* __restrict__ c2, float* __restrict__ s1,
                         float* __restrict__ s2) {
  const int i = blockIdx.x * 4 + (threadIdx.x >> 6);
  const int lane = threadIdx.x & 63;
  float4 hv = *(const float4*)(h + (size_t)i * FD + lane * 4);
  float4 u = *(const float4*)(c1 + lane * 4);
  float4 v = *(const float4*)(c2 + lane * 4);
  float d1 = hv.x * u.x + hv.y * u.y + hv.z * u.z + hv.w * u.w;
  float d2 = hv.x * v.x + hv.y * v.y + hv.z * v.z + hv.w * v.w;
#pragma unroll
  for (int m = 1; m < 64; m <<= 1) {
    d1 += __shfl_xor(d1, m, 64);
    d2 += __shfl_xor(d2, m, 64);
  }
  if (lane == 0) {
    s1[i] = d1;
    s2[i] = d2;
  }
}

// ---------------- kernel 2: WhT[f][i] = bf16( (h @ W^T)[i][f] ), fp32 compute -
__launch_bounds__(256)
__global__ void gat_wht(const float* __restrict__ h, const float* __restrict__ W,
                        unsigned short* __restrict__ whT) {
  __shared__ __align__(16) float hT[64][64];  // [k][i]
  __shared__ __align__(16) float wT[64][64];  // [k][f]
  const int t = threadIdx.x;
  const int i0 = blockIdx.x * 64;
  const int f0 = blockIdx.y * 64;
  const int r = t & 63;
  const int kq = t >> 6;
  const int ty = t >> 4;  // row group (i)
  const int tx = t & 15;  // col group (f)
  float acc[4][4] = {};
  for (int k0 = 0; k0 < FD; k0 += 64) {
#pragma unroll
    for (int kk = 0; kk < 16; kk += 4) {
      float4 v = *(const float4*)(h + (size_t)(i0 + r) * FD + k0 + kq * 16 + kk);
      hT[kq * 16 + kk + 0][r] = v.x;
      hT[kq * 16 + kk + 1][r] = v.y;
      hT[kq * 16 + kk + 2][r] = v.z;
      hT[kq * 16 + kk + 3][r] = v.w;
      float4 u = *(const float4*)(W + (size_t)(f0 + r) * FD + k0 + kq * 16 + kk);
      wT[kq * 16 + kk + 0][r] = u.x;
      wT[kq * 16 + kk + 1][r] = u.y;
      wT[kq * 16 + kk + 2][r] = u.z;
      wT[kq * 16 + kk + 3][r] = u.w;
    }
    __syncthreads();
#pragma unroll 8
    for (int kk = 0; kk < 64; ++kk) {
      float4 av = *(const float4*)&hT[kk][ty * 4];
      float4 bv = *(const float4*)&wT[kk][tx * 4];
      acc[0][0] = fmaf(av.x, bv.x, acc[0][0]);
      acc[0][1] = fmaf(av.x, bv.y, acc[0][1]);
      acc[0][2] = fmaf(av.x, bv.z, acc[0][2]);
      acc[0][3] = fmaf(av.x, bv.w, acc[0][3]);
      acc[1][0] = fmaf(av.y, bv.x, acc[1][0]);
      acc[1][1] = fmaf(av.y, bv.y, acc[1][1]);
      acc[1][2] = fmaf(av.y, bv.z, acc[1][2]);
      acc[1][3] = fmaf(av.y, bv.w, acc[1][3]);
      acc[2][0] = fmaf(av.z, bv.x, acc[2][0]);
      acc[2][1] = fmaf(av.z, bv.y, acc[2][1]);
      acc[2][2] = fmaf(av.z, bv.z, acc[2][2]);
      acc[2][3] = fmaf(av.z, bv.w, acc[2][3]);
      acc[3][0] = fmaf(av.w, bv.x, acc[3][0]);
      acc[3][1] = fmaf(av.w, bv.y, acc[3][1]);
      acc[3][2] = fmaf(av.w, bv.z, acc[3][2]);
      acc[3][3] = fmaf(av.w, bv.w, acc[3][3]);
    }
    __syncthreads();
  }
#pragma unroll
  for (int j = 0; j < 4; ++j) {
    ushort4 o;
    o.x = f2bf(acc[0][j]);
    o.y = f2bf(acc[1][j]);
    o.z = f2bf(acc[2][j]);
    o.w = f2bf(acc[3][j]);
    *(ushort4*)(whT + (size_t)(f0 + tx * 4 + j) * NN + i0 + ty * 4) = o;
  }
}

// ---- build one MFMA A-fragment worth of P (8 cols) directly in registers ----
__device__ __forceinline__ bf16x8_t make_afrag(float s1r, const float4& slo,
                                               const float4& shi, const int4& ml,
                                               const int4& mh, float& lsum) {
  const float sv[8] = {slo.x, slo.y, slo.z, slo.w, shi.x, shi.y, shi.z, shi.w};
  const int mm[8] = {ml.x, ml.y, ml.z, ml.w, mh.x, mh.y, mh.z, mh.w};
  u16x8_t ru;
#pragma unroll
  for (int c = 0; c < 8; ++c) {
    float e = s1r + sv[c];
    e = fmaxf(e, SLOPE * e);
    float pv = mm[c] != 0 ? __expf(e) : 0.f;
    lsum += pv;
    ru[c] = f2bf(pv);
  }
  return __builtin_bit_cast(bf16x8_t, ru);
}

// ---------------- kernel 3: barrier-free fused attention, SW-pipelined ------
// One wave = 32 rows x 128 f-cols x 2048-k slice; P built per-lane directly in
// MFMA A-fragment layout; no LDS, no barriers. Explicit register rotation:
// iter kk issues (a) B-frags for kk (L2 ~250cy, hidden under afrag VALU) and
// (b) adj/s2 for kk+32 (HBM ~900cy, consumed a full iteration later).
__launch_bounds__(256, 2)
__global__ void gat_attn(const int* __restrict__ adj, const float* __restrict__ s1g,
                         const float* __restrict__ s2g,
                         const unsigned short* __restrict__ whT,
                         float* __restrict__ accP, float* __restrict__ lP) {
  const int lane = threadIdx.x & 63;
  const int w = threadIdx.x >> 6;
  const int rs = blockIdx.x >> 1;                  // 0..255 (32-row sets)
  const int ks = (blockIdx.x & 1) * 2 + (w >> 1);  // 0..3 (2048-k slices)
  const int fh = w & 1;                            // 0..1 (128-f halves)
  const int kbase = ks * 2048;
  const int f0 = fh * 128;
  const int r16 = lane & 15;
  const int kg = lane >> 4;  // k-group 0..3 (8 k each)

  const int row0 = rs * 32 + r16;
  const int* arow0 = adj + (size_t)row0 * NN + kbase + kg * 8;
  const int* arow1 = arow0 + (size_t)16 * NN;
  const float* s2p = s2g + kbase + kg * 8;
  const unsigned short* bp = whT + (size_t)(f0 + r16) * NN + kbase + kg * 8;

  const float s1r0 = s1g[row0];
  const float s1r1 = s1g[row0 + 16];

  f32x4_t acc[2][8];
  const f32x4_t zero4 = {0.f, 0.f, 0.f, 0.f};
#pragma unroll
  for (int rt = 0; rt < 2; ++rt)
#pragma unroll
    for (int ct = 0; ct < 8; ++ct) acc[rt][ct] = zero4;

  float l0 = 0.f, l1 = 0.f;

  // ---- prologue: iteration 0's adj/s2 in registers ----
  int4 cm0l = *(const int4*)(arow0 + 0);
  int4 cm0h = *(const int4*)(arow0 + 4);
  int4 cm1l = *(const int4*)(arow1 + 0);
  int4 cm1h = *(const int4*)(arow1 + 4);
  float4 csl = *(const float4*)(s2p + 0);
  float4 csh = *(const float4*)(s2p + 4);

  for (int kk = 0; kk < 2048; kk += 32) {
    // (a) B-frags for CURRENT kk — L2 latency hides under afrag VALU below
    bf16x8_t b0 = *(const bf16x8_t*)(bp + (size_t)0 * 16 * NN + kk);
    bf16x8_t b1 = *(const bf16x8_t*)(bp + (size_t)1 * 16 * NN + kk);
    bf16x8_t b2 = *(const bf16x8_t*)(bp + (size_t)2 * 16 * NN + kk);
    bf16x8_t b3 = *(const bf16x8_t*)(bp + (size_t)3 * 16 * NN + kk);
    bf16x8_t b4 = *(const bf16x8_t*)(bp + (size_t)4 * 16 * NN + kk);
    bf16x8_t b5 = *(const bf16x8_t*)(bp + (size_t)5 * 16 * NN + kk);
    bf16x8_t b6 = *(const bf16x8_t*)(bp + (size_t)6 * 16 * NN + kk);
    bf16x8_t b7 = *(const bf16x8_t*)(bp + (size_t)7 * 16 * NN + kk);

    // (b) NEXT iteration's adj/s2 — HBM latency spans the whole iteration
    const int kn = (kk + 32 < 2048) ? kk + 32 : kk;
    int4 nm0l = *(const int4*)(arow0 + kn);
    int4 nm0h = *(const int4*)(arow0 + kn + 4);
    int4 nm1l = *(const int4*)(arow1 + kn);
    int4 nm1h = *(const int4*)(arow1 + kn + 4);
    float4 nsl = *(const float4*)(s2p + kn);
    float4 nsh = *(const float4*)(s2p + kn + 4);

    // (c) afrags from CURRENT registers (pure VALU, no memory wait)
    bf16x8_t af0 = make_afrag(s1r0, csl, csh, cm0l, cm0h, l0);
    bf16x8_t af1 = make_afrag(s1r1, csl, csh, cm1l, cm1h, l1);

    // (d) MFMA
    acc[0][0] = __builtin_amdgcn_mfma_f32_16x16x32_bf16(af0, b0, acc[0][0], 0, 0, 0);
    acc[1][0] = __builtin_amdgcn_mfma_f32_16x16x32_bf16(af1, b0, acc[1][0], 0, 0, 0);
    acc[0][1] = __builtin_amdgcn_mfma_f32_16x16x32_bf16(af0, b1, acc[0][1], 0, 0, 0);
    acc[1][1] = __builtin_amdgcn_mfma_f32_16x16x32_bf16(af1, b1, acc[1][1], 0, 0, 0);
    acc[0][2] = __builtin_amdgcn_mfma_f32_16x16x32_bf16(af0, b2, acc[0][2], 0, 0, 0);
    acc[1][2] = __builtin_amdgcn_mfma_f32_16x16x32_bf16(af1, b2, acc[1][2], 0, 0, 0);
    acc[0][3] = __builtin_amdgcn_mfma_f32_16x16x32_bf16(af0, b3, acc[0][3], 0, 0, 0);
    acc[1][3] = __builtin_amdgcn_mfma_f32_16x16x32_bf16(af1, b3, acc[1][3], 0, 0, 0);
    acc[0][4] = __builtin_amdgcn_mfma_f32_16x16x32_bf16(af0, b4, acc[0][4], 0, 0, 0);
    acc[1][4] = __builtin_amdgcn_mfma_f32_16x16x32_bf16(af1, b4, acc[1][4], 0, 0, 0);
    acc[0][5] = __builtin_amdgcn_mfma_f32_16x16x32_bf16(af0, b5, acc[0][5], 0, 0, 0);
    acc[1][5] = __builtin_amdgcn_mfma_f32_16x16x32_bf16(af1, b5, acc[1][5], 0, 0, 0);
    acc[0][6] = __builtin_amdgcn_mfma_f32_16x16x32_bf16(af0, b6, acc[0][6], 0, 0, 0);
    acc[1][6] = __builtin_amdgcn_mfma_f32_16x16x32_bf16(af1, b6, acc[1][6], 0, 0, 0);
    acc[0][7] = __builtin_amdgcn_mfma_f32_16x16x32_bf16(af0, b7, acc[0][7], 0, 0, 0);
    acc[1][7] = __builtin_amdgcn_mfma_f32_16x16x32_bf16(af1, b7, acc[1][7], 0, 0, 0);

    // (e) rotate
    cm0l = nm0l; cm0h = nm0h; cm1l = nm1l; cm1h = nm1h;
    csl = nsl; csh = nsh;
  }

  // ---- row-sum l across the 4 k-group lanes of each row ----
  l0 += __shfl_xor(l0, 16, 64);
  l0 += __shfl_xor(l0, 32, 64);
  l1 += __shfl_xor(l1, 16, 64);
  l1 += __shfl_xor(l1, 32, 64);
  if (fh == 0 && kg == 0) {
    lP[(size_t)ks * NN + row0] = l0;
    lP[(size_t)ks * NN + row0 + 16] = l1;
  }

  // ---- write partial acc: row = rs*32 + rt*16 + kg*4 + g, col = f0+ct*16+r16
  float* ap = accP + (size_t)ks * NN * FD;
#pragma unroll
  for (int rt = 0; rt < 2; ++rt) {
#pragma unroll
    for (int ct = 0; ct < 8; ++ct) {
      const int col = f0 + ct * 16 + r16;
#pragma unroll
      for (int g = 0; g < 4; ++g) {
        const int row = rs * 32 + rt * 16 + kg * 4 + g;
        ap[(size_t)row * FD + col] = acc[rt][ct][g];
      }
    }
  }
}

// ---------------- kernel 4: merge partials, divide by l ----------------------
__global__ void gat_merge(const float* __restrict__ accP, const float* __restrict__ lP,
                          float* __restrict__ out, int nsplit) {
  const int i = blockIdx.x;
  const int f = threadIdx.x;
  float s = 0.f, l = 0.f;
  for (int q = 0; q < nsplit; ++q) {
    s += accP[((size_t)q * NN + i) * FD + f];
    l += lP[(size_t)q * NN + i];
  }
  out[(size_t)i * FD + f] = s / l;
}

extern "C" void kernel_launch(void* const* d_in, const int* in_sizes, int n_in,
                              void* d_out, int out_size, void* d_ws, size_t ws_size,
                              hipStream_t stream) {
  const float* h = (const float*)d_in[0];
  const int* adj = (const int*)d_in[1];
  const float* W = (const float*)d_in[2];
  const float* a = (const float*)d_in[3];
  float* out = (float*)d_out;

  char* ws = (char*)d_ws;
  unsigned short* whT = (unsigned short*)ws;          // 256*8192*2 = 4 MB
  float* s1 = (float*)(ws + 4194304);                 // 32 KB
  float* s2 = (float*)(ws + 4194304 + 32768);         // 32 KB
  float* c1 = (float*)(ws + 4194304 + 65536);         // 1 KB
  float* c2 = (float*)(ws + 4194304 + 65536 + 1024);  // 1 KB
  const size_t partOff = 5ull * 1024 * 1024;
  float* accP = (float*)(ws + partOff);                     // 4 x 8 MB
  float* lP = (float*)(ws + partOff + 4ull * NN * FD * 4);  // 4 x 32 KB

  gat_cvec<<<1, 256, 0, stream>>>(W, a, c1, c2);
  gat_svec<<<NN / 4, 256, 0, stream>>>(h, c1, c2, s1, s2);
  gat_wht<<<dim3(NN / 64, FD / 64), 256, 0, stream>>>(h, W, whT);
  gat_attn<<<512, 256, 0, stream>>>(adj, s1, s2, whT, accP, lP);
  gat_merge<<<NN, FD, 0, stream>>>(accP, lP, out, 4);
}

// Round 7
// 315.251 us; speedup vs baseline: 1.5608x; 1.0458x over previous
//
#include <hip/hip_runtime.h>
#include <hip/hip_bf16.h>
#include <stdint.h>

#define NN 8192
#define FD 256
#define SLOPE 0.2f

typedef float f32x4_t __attribute__((ext_vector_type(4)));
typedef __bf16 bf16x8_t __attribute__((ext_vector_type(8)));
typedef unsigned short u16x8_t __attribute__((ext_vector_type(8)));

__device__ __forceinline__ unsigned short f2bf(float x) {
  unsigned int u = __builtin_bit_cast(unsigned int, x);
  u += 0x7FFFu + ((u >> 16) & 1u);  // RNE
  return (unsigned short)(u >> 16);
}

// ---------------- kernel 0: c1/c2[k] = sum_f W[f][k]*a{1,2}[f] ----------------
__global__ void gat_cvec(const float* __restrict__ W, const float* __restrict__ a,
                         float* __restrict__ c1, float* __restrict__ c2) {
  const int k = threadIdx.x;
  float acc1 = 0.f, acc2 = 0.f;
#pragma unroll 8
  for (int f = 0; f < FD; ++f) {
    float w = W[f * FD + k];
    acc1 = fmaf(w, a[f], acc1);
    acc2 = fmaf(w, a[FD + f], acc2);
  }
  c1[k] = acc1;
  c2[k] = acc2;
}

// ---------------- kernel 1: s1/s2[i] = h[i] . c1/c2  (one wave per row) ------
__global__ void gat_svec(const float* __restrict__ h, const float* __restrict__ c1,
                         const float* __restrict__ c2, float* __restrict__ s1,
                         float* __restrict__ s2) {
  const int i = blockIdx.x * 4 + (threadIdx.x >> 6);
  const int lane = threadIdx.x & 63;
  float4 hv = *(const float4*)(h + (size_t)i * FD + lane * 4);
  float4 u = *(const float4*)(c1 + lane * 4);
  float4 v = *(const float4*)(c2 + lane * 4);
  float d1 = hv.x * u.x + hv.y * u.y + hv.z * u.z + hv.w * u.w;
  float d2 = hv.x * v.x + hv.y * v.y + hv.z * v.z + hv.w * v.w;
#pragma unroll
  for (int m = 1; m < 64; m <<= 1) {
    d1 += __shfl_xor(d1, m, 64);
    d2 += __shfl_xor(d2, m, 64);
  }
  if (lane == 0) {
    s1[i] = d1;
    s2[i] = d2;
  }
}

// ---------------- kernel 2: WhT[f][i] = bf16( (h @ W^T)[i][f] ), fp32 compute -
__launch_bounds__(256)
__global__ void gat_wht(const float* __restrict__ h, const float* __restrict__ W,
                        unsigned short* __restrict__ whT) {
  __shared__ __align__(16) float hT[64][64];  // [k][i]
  __shared__ __align__(16) float wT[64][64];  // [k][f]
  const int t = threadIdx.x;
  const int i0 = blockIdx.x * 64;
  const int f0 = blockIdx.y * 64;
  const int r = t & 63;
  const int kq = t >> 6;
  const int ty = t >> 4;  // row group (i)
  const int tx = t & 15;  // col group (f)
  float acc[4][4] = {};
  for (int k0 = 0; k0 < FD; k0 += 64) {
#pragma unroll
    for (int kk = 0; kk < 16; kk += 4) {
      float4 v = *(const float4*)(h + (size_t)(i0 + r) * FD + k0 + kq * 16 + kk);
      hT[kq * 16 + kk + 0][r] = v.x;
      hT[kq * 16 + kk + 1][r] = v.y;
      hT[kq * 16 + kk + 2][r] = v.z;
      hT[kq * 16 + kk + 3][r] = v.w;
      float4 u = *(const float4*)(W + (size_t)(f0 + r) * FD + k0 + kq * 16 + kk);
      wT[kq * 16 + kk + 0][r] = u.x;
      wT[kq * 16 + kk + 1][r] = u.y;
      wT[kq * 16 + kk + 2][r] = u.z;
      wT[kq * 16 + kk + 3][r] = u.w;
    }
    __syncthreads();
#pragma unroll 8
    for (int kk = 0; kk < 64; ++kk) {
      float4 av = *(const float4*)&hT[kk][ty * 4];
      float4 bv = *(const float4*)&wT[kk][tx * 4];
      acc[0][0] = fmaf(av.x, bv.x, acc[0][0]);
      acc[0][1] = fmaf(av.x, bv.y, acc[0][1]);
      acc[0][2] = fmaf(av.x, bv.z, acc[0][2]);
      acc[0][3] = fmaf(av.x, bv.w, acc[0][3]);
      acc[1][0] = fmaf(av.y, bv.x, acc[1][0]);
      acc[1][1] = fmaf(av.y, bv.y, acc[1][1]);
      acc[1][2] = fmaf(av.y, bv.z, acc[1][2]);
      acc[1][3] = fmaf(av.y, bv.w, acc[1][3]);
      acc[2][0] = fmaf(av.z, bv.x, acc[2][0]);
      acc[2][1] = fmaf(av.z, bv.y, acc[2][1]);
      acc[2][2] = fmaf(av.z, bv.z, acc[2][2]);
      acc[2][3] = fmaf(av.z, bv.w, acc[2][3]);
      acc[3][0] = fmaf(av.w, bv.x, acc[3][0]);
      acc[3][1] = fmaf(av.w, bv.y, acc[3][1]);
      acc[3][2] = fmaf(av.w, bv.z, acc[3][2]);
      acc[3][3] = fmaf(av.w, bv.w, acc[3][3]);
    }
    __syncthreads();
  }
#pragma unroll
  for (int j = 0; j < 4; ++j) {
    ushort4 o;
    o.x = f2bf(acc[0][j]);
    o.y = f2bf(acc[1][j]);
    o.z = f2bf(acc[2][j]);
    o.w = f2bf(acc[3][j]);
    *(ushort4*)(whT + (size_t)(f0 + tx * 4 + j) * NN + i0 + ty * 4) = o;
  }
}

// ---------------- kernel 3: pack adj (int32 0/1) -> bitmask, streaming -------
// Each thread packs 32 consecutive ints (8 x int4 loads) into one u32.
// Pure TLP streaming: 2048 blocks x 256 thr, 4 grid-stride passes.
__global__ void gat_pack(const int* __restrict__ adj, unsigned int* __restrict__ mask) {
  const size_t nwords = (size_t)NN * NN / 32;
  size_t idx = (size_t)blockIdx.x * blockDim.x + threadIdx.x;
  const size_t stride = (size_t)gridDim.x * blockDim.x;
  for (; idx < nwords; idx += stride) {
    const int4* p = (const int4*)(adj + idx * 32);
    unsigned int m = 0;
#pragma unroll
    for (int j = 0; j < 8; ++j) {
      int4 v = p[j];
      m |= (v.x != 0 ? 1u : 0u) << (j * 4 + 0);
      m |= (v.y != 0 ? 1u : 0u) << (j * 4 + 1);
      m |= (v.z != 0 ? 1u : 0u) << (j * 4 + 2);
      m |= (v.w != 0 ? 1u : 0u) << (j * 4 + 3);
    }
    mask[idx] = m;
  }
}

// ---- build one MFMA A-fragment worth of P (8 cols) from an 8-bit mask -------
__device__ __forceinline__ bf16x8_t make_afrag(float s1r, const float4& slo,
                                               const float4& shi, unsigned int mbyte,
                                               float& lsum) {
  const float sv[8] = {slo.x, slo.y, slo.z, slo.w, shi.x, shi.y, shi.z, shi.w};
  u16x8_t ru;
#pragma unroll
  for (int c = 0; c < 8; ++c) {
    float e = s1r + sv[c];
    e = fmaxf(e, SLOPE * e);
    float pv = ((mbyte >> c) & 1u) ? __expf(e) : 0.f;
    lsum += pv;
    ru[c] = f2bf(pv);
  }
  return __builtin_bit_cast(bf16x8_t, ru);
}

// ---------------- kernel 4: fused attention on bitmask, in-block ks-reduce ---
// grid 256 x 512 thr, 1 block/CU. Block = 32 rows; 8 waves = {4 ks} x {2 fh}.
// Wave = 32 rows x 128 f x 2048-k slice; no LDS in main loop, no barriers.
// adj read as bits (mask word per row per 32-k iter); whT/mask/s2 L2-resident.
// End: one LDS reduction over the 4 ks-slices, write final out (no merge pass).
__launch_bounds__(512, 2)
__global__ void gat_attn(const unsigned int* __restrict__ maskp,
                         const float* __restrict__ s1g, const float* __restrict__ s2g,
                         const unsigned short* __restrict__ whT,
                         float* __restrict__ out) {
  __shared__ float red[8][32][129];  // [wave][row][col(fh-local)] +1 pad, 132 KB
  __shared__ float lred[4][32];      // [ks][row]

  const int tid = threadIdx.x;
  const int lane = tid & 63;
  const int w = tid >> 6;
  const int fh = w & 1;    // f half: cols fh*128..+127
  const int ksw = w >> 1;  // 0..3 k-slice
  const int kbase = ksw * 2048;
  const int f0 = fh * 128;
  const int r16 = lane & 15;
  const int kg = lane >> 4;  // 8-k group within 32-k chunk
  const int i0 = blockIdx.x * 32;
  const int row0 = i0 + r16;

  const unsigned int* mrow0 = maskp + (size_t)row0 * (NN / 32) + (kbase >> 5);
  const unsigned int* mrow1 = mrow0 + (size_t)16 * (NN / 32);
  const float* s2p = s2g + kbase + kg * 8;
  const unsigned short* bp = whT + (size_t)(f0 + r16) * NN + kbase + kg * 8;

  const float s1r0 = s1g[row0];
  const float s1r1 = s1g[row0 + 16];

  f32x4_t acc[2][8];
  const f32x4_t zero4 = {0.f, 0.f, 0.f, 0.f};
#pragma unroll
  for (int rt = 0; rt < 2; ++rt)
#pragma unroll
    for (int ct = 0; ct < 8; ++ct) acc[rt][ct] = zero4;

  float l0 = 0.f, l1 = 0.f;

  // ---- prologue: iter-0 mask words + s2 ----
  unsigned int cw0 = mrow0[0];
  unsigned int cw1 = mrow1[0];
  float4 csl = *(const float4*)(s2p);
  float4 csh = *(const float4*)(s2p + 4);

  for (int kk = 0; kk < 2048; kk += 32) {
    // B-frags for current kk (L2-resident whT; hides under afrag VALU)
    bf16x8_t b0 = *(const bf16x8_t*)(bp + (size_t)0 * 16 * NN + kk);
    bf16x8_t b1 = *(const bf16x8_t*)(bp + (size_t)1 * 16 * NN + kk);
    bf16x8_t b2 = *(const bf16x8_t*)(bp + (size_t)2 * 16 * NN + kk);
    bf16x8_t b3 = *(const bf16x8_t*)(bp + (size_t)3 * 16 * NN + kk);
    bf16x8_t b4 = *(const bf16x8_t*)(bp + (size_t)4 * 16 * NN + kk);
    bf16x8_t b5 = *(const bf16x8_t*)(bp + (size_t)5 * 16 * NN + kk);
    bf16x8_t b6 = *(const bf16x8_t*)(bp + (size_t)6 * 16 * NN + kk);
    bf16x8_t b7 = *(const bf16x8_t*)(bp + (size_t)7 * 16 * NN + kk);

    // next iter's mask/s2
    const int kn = (kk + 32 < 2048) ? kk + 32 : kk;
    unsigned int nw0 = mrow0[kn >> 5];
    unsigned int nw1 = mrow1[kn >> 5];
    float4 nsl = *(const float4*)(s2p + kn);
    float4 nsh = *(const float4*)(s2p + kn + 4);

    // P fragments from current registers
    bf16x8_t af0 = make_afrag(s1r0, csl, csh, (cw0 >> (kg * 8)) & 0xffu, l0);
    bf16x8_t af1 = make_afrag(s1r1, csl, csh, (cw1 >> (kg * 8)) & 0xffu, l1);

    acc[0][0] = __builtin_amdgcn_mfma_f32_16x16x32_bf16(af0, b0, acc[0][0], 0, 0, 0);
    acc[1][0] = __builtin_amdgcn_mfma_f32_16x16x32_bf16(af1, b0, acc[1][0], 0, 0, 0);
    acc[0][1] = __builtin_amdgcn_mfma_f32_16x16x32_bf16(af0, b1, acc[0][1], 0, 0, 0);
    acc[1][1] = __builtin_amdgcn_mfma_f32_16x16x32_bf16(af1, b1, acc[1][1], 0, 0, 0);
    acc[0][2] = __builtin_amdgcn_mfma_f32_16x16x32_bf16(af0, b2, acc[0][2], 0, 0, 0);
    acc[1][2] = __builtin_amdgcn_mfma_f32_16x16x32_bf16(af1, b2, acc[1][2], 0, 0, 0);
    acc[0][3] = __builtin_amdgcn_mfma_f32_16x16x32_bf16(af0, b3, acc[0][3], 0, 0, 0);
    acc[1][3] = __builtin_amdgcn_mfma_f32_16x16x32_bf16(af1, b3, acc[1][3], 0, 0, 0);
    acc[0][4] = __builtin_amdgcn_mfma_f32_16x16x32_bf16(af0, b4, acc[0][4], 0, 0, 0);
    acc[1][4] = __builtin_amdgcn_mfma_f32_16x16x32_bf16(af1, b4, acc[1][4], 0, 0, 0);
    acc[0][5] = __builtin_amdgcn_mfma_f32_16x16x32_bf16(af0, b5, acc[0][5], 0, 0, 0);
    acc[1][5] = __builtin_amdgcn_mfma_f32_16x16x32_bf16(af1, b5, acc[1][5], 0, 0, 0);
    acc[0][6] = __builtin_amdgcn_mfma_f32_16x16x32_bf16(af0, b6, acc[0][6], 0, 0, 0);
    acc[1][6] = __builtin_amdgcn_mfma_f32_16x16x32_bf16(af1, b6, acc[1][6], 0, 0, 0);
    acc[0][7] = __builtin_amdgcn_mfma_f32_16x16x32_bf16(af0, b7, acc[0][7], 0, 0, 0);
    acc[1][7] = __builtin_amdgcn_mfma_f32_16x16x32_bf16(af1, b7, acc[1][7], 0, 0, 0);

    cw0 = nw0; cw1 = nw1; csl = nsl; csh = nsh;
  }

  // ---- per-wave l: sum across the 4 kg lanes of each row ----
  l0 += __shfl_xor(l0, 16, 64);
  l0 += __shfl_xor(l0, 32, 64);
  l1 += __shfl_xor(l1, 16, 64);
  l1 += __shfl_xor(l1, 32, 64);
  if (fh == 0 && lane < 16) {
    lred[ksw][lane] = l0;
    lred[ksw][lane + 16] = l1;
  }

  // ---- stage acc into LDS: red[w][row][col within fh-half] ----
#pragma unroll
  for (int rt = 0; rt < 2; ++rt) {
#pragma unroll
    for (int ct = 0; ct < 8; ++ct) {
      const int colw = ct * 16 + r16;
#pragma unroll
      for (int g = 0; g < 4; ++g) {
        red[w][rt * 16 + kg * 4 + g][colw] = acc[rt][ct][g];
      }
    }
  }
  __syncthreads();

  // ---- reduce 4 ks-slices, divide by l, write final out ----
  const int orow = tid >> 4;             // 0..31
  const int cb16 = (tid & 15) * 16;      // 16 cols per thread
  const float lsum = lred[0][orow] + lred[1][orow] + lred[2][orow] + lred[3][orow];
  const float inv = 1.0f / lsum;
  float ov[16];
#pragma unroll
  for (int c = 0; c < 16; ++c) {
    const int col = cb16 + c;
    const int fhc = col >> 7;
    const int cw = col & 127;
    const float s = red[fhc][orow][cw] + red[2 + fhc][orow][cw] +
                    red[4 + fhc][orow][cw] + red[6 + fhc][orow][cw];
    ov[c] = s * inv;
  }
  float* op = out + (size_t)(i0 + orow) * FD + cb16;
#pragma unroll
  for (int c = 0; c < 16; c += 4) {
    float4 o4 = {ov[c], ov[c + 1], ov[c + 2], ov[c + 3]};
    *(float4*)(op + c) = o4;
  }
}

extern "C" void kernel_launch(void* const* d_in, const int* in_sizes, int n_in,
                              void* d_out, int out_size, void* d_ws, size_t ws_size,
                              hipStream_t stream) {
  const float* h = (const float*)d_in[0];
  const int* adj = (const int*)d_in[1];
  const float* W = (const float*)d_in[2];
  const float* a = (const float*)d_in[3];
  float* out = (float*)d_out;

  char* ws = (char*)d_ws;
  unsigned short* whT = (unsigned short*)ws;          // 4 MB
  float* s1 = (float*)(ws + 4194304);                 // 32 KB
  float* s2 = (float*)(ws + 4194304 + 32768);         // 32 KB
  float* c1 = (float*)(ws + 4194304 + 65536);         // 1 KB
  float* c2 = (float*)(ws + 4194304 + 65536 + 1024);  // 1 KB
  unsigned int* maskp = (unsigned int*)(ws + 5242880);  // 8 MB @ 5 MB offset

  gat_pack<<<2048, 256, 0, stream>>>(adj, maskp);
  gat_cvec<<<1, 256, 0, stream>>>(W, a, c1, c2);
  gat_svec<<<NN / 4, 256, 0, stream>>>(h, c1, c2, s1, s2);
  gat_wht<<<dim3(NN / 64, FD / 64), 256, 0, stream>>>(h, W, whT);
  gat_attn<<<NN / 32, 512, 0, stream>>>(maskp, s1, s2, whT, out);
}

// Round 8
// 275.519 us; speedup vs baseline: 1.7858x; 1.1442x over previous
//
#include <hip/hip_runtime.h>
#include <hip/hip_bf16.h>
#include <stdint.h>

#define NN 8192
#define FD 256
#define SLOPE 0.2f

typedef float f32x4_t __attribute__((ext_vector_type(4)));
typedef __bf16 bf16x8_t __attribute__((ext_vector_type(8)));
typedef unsigned short u16x8_t __attribute__((ext_vector_type(8)));

__device__ __forceinline__ unsigned short f2bf(float x) {
  unsigned int u = __builtin_bit_cast(unsigned int, x);
  u += 0x7FFFu + ((u >> 16) & 1u);  // RNE
  return (unsigned short)(u >> 16);
}

// ---------------- kernel 0: c1/c2[k] = sum_f W[f][k]*a{1,2}[f] ----------------
__global__ void gat_cvec(const float* __restrict__ W, const float* __restrict__ a,
                         float* __restrict__ c1, float* __restrict__ c2) {
  const int k = threadIdx.x;
  float acc1 = 0.f, acc2 = 0.f;
#pragma unroll 8
  for (int f = 0; f < FD; ++f) {
    float w = W[f * FD + k];
    acc1 = fmaf(w, a[f], acc1);
    acc2 = fmaf(w, a[FD + f], acc2);
  }
  c1[k] = acc1;
  c2[k] = acc2;
}

// ---------------- kernel 1: s1/s2[i] = h[i] . c1/c2  (one wave per row) ------
__global__ void gat_svec(const float* __restrict__ h, const float* __restrict__ c1,
                         const float* __restrict__ c2, float* __restrict__ s1,
                         float* __restrict__ s2) {
  const int i = blockIdx.x * 4 + (threadIdx.x >> 6);
  const int lane = threadIdx.x & 63;
  float4 hv = *(const float4*)(h + (size_t)i * FD + lane * 4);
  float4 u = *(const float4*)(c1 + lane * 4);
  float4 v = *(const float4*)(c2 + lane * 4);
  float d1 = hv.x * u.x + hv.y * u.y + hv.z * u.z + hv.w * u.w;
  float d2 = hv.x * v.x + hv.y * v.y + hv.z * v.z + hv.w * v.w;
#pragma unroll
  for (int m = 1; m < 64; m <<= 1) {
    d1 += __shfl_xor(d1, m, 64);
    d2 += __shfl_xor(d2, m, 64);
  }
  if (lane == 0) {
    s1[i] = d1;
    s2[i] = d2;
  }
}

// ---------------- kernel 2: WhT[f][i] = bf16( (h @ W^T)[i][f] ), fp32 compute -
__launch_bounds__(256)
__global__ void gat_wht(const float* __restrict__ h, const float* __restrict__ W,
                        unsigned short* __restrict__ whT) {
  __shared__ __align__(16) float hT[64][64];  // [k][i]
  __shared__ __align__(16) float wT[64][64];  // [k][f]
  const int t = threadIdx.x;
  const int i0 = blockIdx.x * 64;
  const int f0 = blockIdx.y * 64;
  const int r = t & 63;
  const int kq = t >> 6;
  const int ty = t >> 4;  // row group (i)
  const int tx = t & 15;  // col group (f)
  float acc[4][4] = {};
  for (int k0 = 0; k0 < FD; k0 += 64) {
#pragma unroll
    for (int kk = 0; kk < 16; kk += 4) {
      float4 v = *(const float4*)(h + (size_t)(i0 + r) * FD + k0 + kq * 16 + kk);
      hT[kq * 16 + kk + 0][r] = v.x;
      hT[kq * 16 + kk + 1][r] = v.y;
      hT[kq * 16 + kk + 2][r] = v.z;
      hT[kq * 16 + kk + 3][r] = v.w;
      float4 u = *(const float4*)(W + (size_t)(f0 + r) * FD + k0 + kq * 16 + kk);
      wT[kq * 16 + kk + 0][r] = u.x;
      wT[kq * 16 + kk + 1][r] = u.y;
      wT[kq * 16 + kk + 2][r] = u.z;
      wT[kq * 16 + kk + 3][r] = u.w;
    }
    __syncthreads();
#pragma unroll 8
    for (int kk = 0; kk < 64; ++kk) {
      float4 av = *(const float4*)&hT[kk][ty * 4];
      float4 bv = *(const float4*)&wT[kk][tx * 4];
      acc[0][0] = fmaf(av.x, bv.x, acc[0][0]);
      acc[0][1] = fmaf(av.x, bv.y, acc[0][1]);
      acc[0][2] = fmaf(av.x, bv.z, acc[0][2]);
      acc[0][3] = fmaf(av.x, bv.w, acc[0][3]);
      acc[1][0] = fmaf(av.y, bv.x, acc[1][0]);
      acc[1][1] = fmaf(av.y, bv.y, acc[1][1]);
      acc[1][2] = fmaf(av.y, bv.z, acc[1][2]);
      acc[1][3] = fmaf(av.y, bv.w, acc[1][3]);
      acc[2][0] = fmaf(av.z, bv.x, acc[2][0]);
      acc[2][1] = fmaf(av.z, bv.y, acc[2][1]);
      acc[2][2] = fmaf(av.z, bv.z, acc[2][2]);
      acc[2][3] = fmaf(av.z, bv.w, acc[2][3]);
      acc[3][0] = fmaf(av.w, bv.x, acc[3][0]);
      acc[3][1] = fmaf(av.w, bv.y, acc[3][1]);
      acc[3][2] = fmaf(av.w, bv.z, acc[3][2]);
      acc[3][3] = fmaf(av.w, bv.w, acc[3][3]);
    }
    __syncthreads();
  }
#pragma unroll
  for (int j = 0; j < 4; ++j) {
    ushort4 o;
    o.x = f2bf(acc[0][j]);
    o.y = f2bf(acc[1][j]);
    o.z = f2bf(acc[2][j]);
    o.w = f2bf(acc[3][j]);
    *(ushort4*)(whT + (size_t)(f0 + tx * 4 + j) * NN + i0 + ty * 4) = o;
  }
}

// ---------------- kernel 3: pack adj -> bitmask via ballot (coalesced) -------
// Wave reads 64 consecutive ints (one coalesced 256B load), __ballot -> one
// 64-bit mask word. 4-deep unroll; lanes 0-3 store the 4 words (32B).
__global__ void gat_pack(const int* __restrict__ adj,
                         unsigned long long* __restrict__ mask64) {
  const int lane = threadIdx.x & 63;
  const int w = threadIdx.x >> 6;
  const size_t ngroups = (size_t)NN * NN / 256;
  const size_t nw = (size_t)gridDim.x * (blockDim.x >> 6);
  for (size_t g = (size_t)blockIdx.x * (blockDim.x >> 6) + w; g < ngroups; g += nw) {
    const int* p = adj + g * 256 + lane;
    int v0 = p[0];
    int v1 = p[64];
    int v2 = p[128];
    int v3 = p[192];
    unsigned long long m0 = __ballot(v0 != 0);
    unsigned long long m1 = __ballot(v1 != 0);
    unsigned long long m2 = __ballot(v2 != 0);
    unsigned long long m3 = __ballot(v3 != 0);
    if (lane < 4) {
      unsigned long long mv = lane == 0 ? m0 : lane == 1 ? m1 : lane == 2 ? m2 : m3;
      mask64[g * 4 + lane] = mv;
    }
  }
}

// ---- build one MFMA A-fragment worth of P (8 cols) from an 8-bit mask -------
__device__ __forceinline__ bf16x8_t make_afrag(float s1r, const float4& slo,
                                               const float4& shi, unsigned int mbyte,
                                               float& lsum) {
  const float sv[8] = {slo.x, slo.y, slo.z, slo.w, shi.x, shi.y, shi.z, shi.w};
  u16x8_t ru;
#pragma unroll
  for (int c = 0; c < 8; ++c) {
    float e = s1r + sv[c];
    e = fmaxf(e, SLOPE * e);
    float pv = ((mbyte >> c) & 1u) ? __expf(e) : 0.f;
    lsum += pv;
    ru[c] = f2bf(pv);
  }
  return __builtin_bit_cast(bf16x8_t, ru);
}

// ---------------- kernel 4: fused attention, 16 waves/block, small acc -------
// grid 256 x 1024 thr (1 block/CU, 16 waves = 4 waves/SIMD). Wave (fh,ksw) =
// 32 rows x 64 f-cols x 2048-k slice: acc only 2x4xf32x4 = 32 regs -> total
// footprint ~100 < 128 cap -> 16 waves resident. Barrier-free main loop (no
// LDS use); one end reduction over ks via 99KB LDS (free at 1 block/CU).
__launch_bounds__(1024, 4)
__global__ void gat_attn(const unsigned int* __restrict__ maskp,
                         const float* __restrict__ s1g, const float* __restrict__ s2g,
                         const unsigned short* __restrict__ whT,
                         float* __restrict__ out) {
  __shared__ float red[3][32][258];  // ks 1..3 partials, ~99 KB
  __shared__ float lred[4][32];

  const int tid = threadIdx.x;
  const int lane = tid & 63;
  const int wid = tid >> 6;   // 0..15
  const int fh = wid & 3;     // f quarter: cols fh*64..+63
  const int ksw = wid >> 2;   // 0..3 k-slice
  const int kbase = ksw * 2048;
  const int f0 = fh * 64;
  const int r16 = lane & 15;
  const int kg = lane >> 4;  // 8-k group within 32-k chunk
  const int i0 = blockIdx.x * 32;
  const int row0 = i0 + r16;

  const unsigned int* mrow0 = maskp + (size_t)row0 * (NN / 32) + (kbase >> 5);
  const unsigned int* mrow1 = mrow0 + (size_t)16 * (NN / 32);
  const float* s2p = s2g + kbase + kg * 8;
  const unsigned short* bp = whT + (size_t)(f0 + r16) * NN + kbase + kg * 8;

  const float s1r0 = s1g[row0];
  const float s1r1 = s1g[row0 + 16];

  f32x4_t acc[2][4];
  const f32x4_t zero4 = {0.f, 0.f, 0.f, 0.f};
#pragma unroll
  for (int rt = 0; rt < 2; ++rt)
#pragma unroll
    for (int ct = 0; ct < 4; ++ct) acc[rt][ct] = zero4;

  float l0 = 0.f, l1 = 0.f;

  unsigned int cw0 = mrow0[0];
  unsigned int cw1 = mrow1[0];
  float4 csl = *(const float4*)(s2p);
  float4 csh = *(const float4*)(s2p + 4);

  for (int kk = 0; kk < 2048; kk += 32) {
    // B-frags for current kk (whT slice L2-resident)
    bf16x8_t b0 = *(const bf16x8_t*)(bp + (size_t)0 * 16 * NN + kk);
    bf16x8_t b1 = *(const bf16x8_t*)(bp + (size_t)1 * 16 * NN + kk);
    bf16x8_t b2 = *(const bf16x8_t*)(bp + (size_t)2 * 16 * NN + kk);
    bf16x8_t b3 = *(const bf16x8_t*)(bp + (size_t)3 * 16 * NN + kk);

    // next iter's mask/s2
    const int kn = (kk + 32 < 2048) ? kk + 32 : kk;
    unsigned int nw0 = mrow0[kn >> 5];
    unsigned int nw1 = mrow1[kn >> 5];
    float4 nsl = *(const float4*)(s2p + kn);
    float4 nsh = *(const float4*)(s2p + kn + 4);

    bf16x8_t af0 = make_afrag(s1r0, csl, csh, (cw0 >> (kg * 8)) & 0xffu, l0);
    bf16x8_t af1 = make_afrag(s1r1, csl, csh, (cw1 >> (kg * 8)) & 0xffu, l1);

    acc[0][0] = __builtin_amdgcn_mfma_f32_16x16x32_bf16(af0, b0, acc[0][0], 0, 0, 0);
    acc[1][0] = __builtin_amdgcn_mfma_f32_16x16x32_bf16(af1, b0, acc[1][0], 0, 0, 0);
    acc[0][1] = __builtin_amdgcn_mfma_f32_16x16x32_bf16(af0, b1, acc[0][1], 0, 0, 0);
    acc[1][1] = __builtin_amdgcn_mfma_f32_16x16x32_bf16(af1, b1, acc[1][1], 0, 0, 0);
    acc[0][2] = __builtin_amdgcn_mfma_f32_16x16x32_bf16(af0, b2, acc[0][2], 0, 0, 0);
    acc[1][2] = __builtin_amdgcn_mfma_f32_16x16x32_bf16(af1, b2, acc[1][2], 0, 0, 0);
    acc[0][3] = __builtin_amdgcn_mfma_f32_16x16x32_bf16(af0, b3, acc[0][3], 0, 0, 0);
    acc[1][3] = __builtin_amdgcn_mfma_f32_16x16x32_bf16(af1, b3, acc[1][3], 0, 0, 0);

    cw0 = nw0; cw1 = nw1; csl = nsl; csh = nsh;
  }

  // ---- l: sum across kg lanes; every lane ends with full row-sum ----
  l0 += __shfl_xor(l0, 16, 64);
  l0 += __shfl_xor(l0, 32, 64);
  l1 += __shfl_xor(l1, 16, 64);
  l1 += __shfl_xor(l1, 32, 64);
  if (fh == 0 && lane < 16) {
    lred[ksw][lane] = l0;
    lred[ksw][lane + 16] = l1;
  }

  // ---- ks 1..3 waves stage partial acc to LDS ----
  if (ksw > 0) {
#pragma unroll
    for (int rt = 0; rt < 2; ++rt) {
#pragma unroll
      for (int ct = 0; ct < 4; ++ct) {
        const int col = f0 + ct * 16 + r16;
#pragma unroll
        for (int g = 0; g < 4; ++g) {
          red[ksw - 1][rt * 16 + kg * 4 + g][col] = acc[rt][ct][g];
        }
      }
    }
  }
  __syncthreads();

  // ---- ks 0 waves: add partials, divide by total l, write out ----
  if (ksw == 0) {
#pragma unroll
    for (int rt = 0; rt < 2; ++rt) {
#pragma unroll
      for (int g = 0; g < 4; ++g) {
        const int rl = rt * 16 + kg * 4 + g;
        const float lt = lred[0][rl] + lred[1][rl] + lred[2][rl] + lred[3][rl];
        const float inv = 1.0f / lt;
#pragma unroll
        for (int ct = 0; ct < 4; ++ct) {
          const int col = f0 + ct * 16 + r16;
          const float s = acc[rt][ct][g] + red[0][rl][col] + red[1][rl][col] + red[2][rl][col];
          out[(size_t)(i0 + rl) * FD + col] = s * inv;
        }
      }
    }
  }
}

extern "C" void kernel_launch(void* const* d_in, const int* in_sizes, int n_in,
                              void* d_out, int out_size, void* d_ws, size_t ws_size,
                              hipStream_t stream) {
  const float* h = (const float*)d_in[0];
  const int* adj = (const int*)d_in[1];
  const float* W = (const float*)d_in[2];
  const float* a = (const float*)d_in[3];
  float* out = (float*)d_out;

  char* ws = (char*)d_ws;
  unsigned short* whT = (unsigned short*)ws;          // 4 MB
  float* s1 = (float*)(ws + 4194304);                 // 32 KB
  float* s2 = (float*)(ws + 4194304 + 32768);         // 32 KB
  float* c1 = (float*)(ws + 4194304 + 65536);         // 1 KB
  float* c2 = (float*)(ws + 4194304 + 65536 + 1024);  // 1 KB
  unsigned long long* mask64 = (unsigned long long*)(ws + 5242880);  // 8 MB

  gat_pack<<<2048, 256, 0, stream>>>(adj, mask64);
  gat_cvec<<<1, 256, 0, stream>>>(W, a, c1, c2);
  gat_svec<<<NN / 4, 256, 0, stream>>>(h, c1, c2, s1, s2);
  gat_wht<<<dim3(NN / 64, FD / 64), 256, 0, stream>>>(h, W, whT);
  gat_attn<<<NN / 32, 1024, 0, stream>>>((const unsigned int*)mask64, s1, s2, whT, out);
}

// Round 9
// 185.190 us; speedup vs baseline: 2.6569x; 1.4878x over previous
//
#include <hip/hip_runtime.h>
#include <hip/hip_bf16.h>
#include <stdint.h>

#define NN 8192
#define FD 256
#define SLOPE 0.2f
#define LOG2E 1.44269504088896f

typedef float f32x4_t __attribute__((ext_vector_type(4)));
typedef __bf16 bf16x8_t __attribute__((ext_vector_type(8)));
typedef unsigned short u16x8_t __attribute__((ext_vector_type(8)));

__device__ __forceinline__ unsigned short f2bf(float x) {
  unsigned int u = __builtin_bit_cast(unsigned int, x);
  u += 0x7FFFu + ((u >> 16) & 1u);  // RNE
  return (unsigned short)(u >> 16);
}

// ---------------- kernel 0: c1/c2[k] = sum_f W[f][k]*a{1,2}[f] ----------------
__global__ void gat_cvec(const float* __restrict__ W, const float* __restrict__ a,
                         float* __restrict__ c1, float* __restrict__ c2) {
  const int k = threadIdx.x;
  float acc1 = 0.f, acc2 = 0.f;
#pragma unroll 8
  for (int f = 0; f < FD; ++f) {
    float w = W[f * FD + k];
    acc1 = fmaf(w, a[f], acc1);
    acc2 = fmaf(w, a[FD + f], acc2);
  }
  c1[k] = acc1;
  c2[k] = acc2;
}

// -------- kernel 1: s1/s2[i] = (h[i].c)*log2e  (pre-scaled for exp2) --------
__global__ void gat_svec(const float* __restrict__ h, const float* __restrict__ c1,
                         const float* __restrict__ c2, float* __restrict__ s1,
                         float* __restrict__ s2) {
  const int i = blockIdx.x * 4 + (threadIdx.x >> 6);
  const int lane = threadIdx.x & 63;
  float4 hv = *(const float4*)(h + (size_t)i * FD + lane * 4);
  float4 u = *(const float4*)(c1 + lane * 4);
  float4 v = *(const float4*)(c2 + lane * 4);
  float d1 = hv.x * u.x + hv.y * u.y + hv.z * u.z + hv.w * u.w;
  float d2 = hv.x * v.x + hv.y * v.y + hv.z * v.z + hv.w * v.w;
#pragma unroll
  for (int m = 1; m < 64; m <<= 1) {
    d1 += __shfl_xor(d1, m, 64);
    d2 += __shfl_xor(d2, m, 64);
  }
  if (lane == 0) {
    s1[i] = d1 * LOG2E;
    s2[i] = d2 * LOG2E;
  }
}

// -------- kernel 2: Wh = h @ W^T (fp32), stored TILED: whT2[i/32][f][i%32] ---
__launch_bounds__(256)
__global__ void gat_wht(const float* __restrict__ h, const float* __restrict__ W,
                        unsigned short* __restrict__ whT2) {
  __shared__ __align__(16) float hT[64][64];  // [k][i]
  __shared__ __align__(16) float wT[64][64];  // [k][f]
  const int t = threadIdx.x;
  const int i0 = blockIdx.x * 64;
  const int f0 = blockIdx.y * 64;
  const int r = t & 63;
  const int kq = t >> 6;
  const int ty = t >> 4;  // row group (i)
  const int tx = t & 15;  // col group (f)
  float acc[4][4] = {};
  for (int k0 = 0; k0 < FD; k0 += 64) {
#pragma unroll
    for (int kk = 0; kk < 16; kk += 4) {
      float4 v = *(const float4*)(h + (size_t)(i0 + r) * FD + k0 + kq * 16 + kk);
      hT[kq * 16 + kk + 0][r] = v.x;
      hT[kq * 16 + kk + 1][r] = v.y;
      hT[kq * 16 + kk + 2][r] = v.z;
      hT[kq * 16 + kk + 3][r] = v.w;
      float4 u = *(const float4*)(W + (size_t)(f0 + r) * FD + k0 + kq * 16 + kk);
      wT[kq * 16 + kk + 0][r] = u.x;
      wT[kq * 16 + kk + 1][r] = u.y;
      wT[kq * 16 + kk + 2][r] = u.z;
      wT[kq * 16 + kk + 3][r] = u.w;
    }
    __syncthreads();
#pragma unroll 8
    for (int kk = 0; kk < 64; ++kk) {
      float4 av = *(const float4*)&hT[kk][ty * 4];
      float4 bv = *(const float4*)&wT[kk][tx * 4];
      acc[0][0] = fmaf(av.x, bv.x, acc[0][0]);
      acc[0][1] = fmaf(av.x, bv.y, acc[0][1]);
      acc[0][2] = fmaf(av.x, bv.z, acc[0][2]);
      acc[0][3] = fmaf(av.x, bv.w, acc[0][3]);
      acc[1][0] = fmaf(av.y, bv.x, acc[1][0]);
      acc[1][1] = fmaf(av.y, bv.y, acc[1][1]);
      acc[1][2] = fmaf(av.y, bv.z, acc[1][2]);
      acc[1][3] = fmaf(av.y, bv.w, acc[1][3]);
      acc[2][0] = fmaf(av.z, bv.x, acc[2][0]);
      acc[2][1] = fmaf(av.z, bv.y, acc[2][1]);
      acc[2][2] = fmaf(av.z, bv.z, acc[2][2]);
      acc[2][3] = fmaf(av.z, bv.w, acc[2][3]);
      acc[3][0] = fmaf(av.w, bv.x, acc[3][0]);
      acc[3][1] = fmaf(av.w, bv.y, acc[3][1]);
      acc[3][2] = fmaf(av.w, bv.z, acc[3][2]);
      acc[3][3] = fmaf(av.w, bv.w, acc[3][3]);
    }
    __syncthreads();
  }
  const int iv = i0 + ty * 4;  // 4 consecutive i -> contiguous in tile
#pragma unroll
  for (int j = 0; j < 4; ++j) {
    const int f = f0 + tx * 4 + j;
    ushort4 o;
    o.x = f2bf(acc[0][j]);
    o.y = f2bf(acc[1][j]);
    o.z = f2bf(acc[2][j]);
    o.w = f2bf(acc[3][j]);
    *(ushort4*)(whT2 + (size_t)(iv >> 5) * (FD * 32) + (size_t)f * 32 + (iv & 31)) = o;
  }
}

// ---------------- kernel 3: pack adj -> bitmask via ballot (coalesced) -------
__global__ void gat_pack(const int* __restrict__ adj,
                         unsigned long long* __restrict__ mask64) {
  const int lane = threadIdx.x & 63;
  const int w = threadIdx.x >> 6;
  const size_t ngroups = (size_t)NN * NN / 256;
  const size_t nw = (size_t)gridDim.x * (blockDim.x >> 6);
  for (size_t g = (size_t)blockIdx.x * (blockDim.x >> 6) + w; g < ngroups; g += nw) {
    const int* p = adj + g * 256 + lane;
    int v0 = p[0];
    int v1 = p[64];
    int v2 = p[128];
    int v3 = p[192];
    unsigned long long m0 = __ballot(v0 != 0);
    unsigned long long m1 = __ballot(v1 != 0);
    unsigned long long m2 = __ballot(v2 != 0);
    unsigned long long m3 = __ballot(v3 != 0);
    if (lane < 4) {
      unsigned long long mv = lane == 0 ? m0 : lane == 1 ? m1 : lane == 2 ? m2 : m3;
      mask64[g * 4 + lane] = mv;
    }
  }
}

// ---- one MFMA A-fragment of P (8 cols) from an 8-bit mask; exp2 domain ------
__device__ __forceinline__ bf16x8_t make_afrag(float s1r, const float4& slo,
                                               const float4& shi, unsigned int mbyte,
                                               float& lsum) {
  const float sv[8] = {slo.x, slo.y, slo.z, slo.w, shi.x, shi.y, shi.z, shi.w};
  u16x8_t ru;
#pragma unroll
  for (int c = 0; c < 8; ++c) {
    float x = s1r + sv[c];           // already log2e-scaled
    x = fmaxf(x, SLOPE * x);         // leaky commutes with positive scale
    float pv = exp2f(x);             // v_exp_f32
    pv = ((mbyte >> c) & 1u) ? pv : 0.f;
    lsum += pv;
    ru[c] = f2bf(pv);
  }
  return __builtin_bit_cast(bf16x8_t, ru);
}

// ---------------- kernel 4: fused attention, P computed once per (i,j) -------
// grid 256 x 512 thr (1 block/CU). Block = 32 rows; 8 waves = 8 k-slices of
// 1024. Wave = 32 rows x FULL 256 f x 1024 k: no P replication. B-frags from
// tiled whT2: per iter the wave's 16 loads cover ONE contiguous 16 KB block
// (each load = 1024 contiguous bytes). Barrier-free main loop; end: 2-phase
// LDS reduction over the 8 ks partials (133 KB, free at 1 block/CU).
__launch_bounds__(512, 2)
__global__ void gat_attn(const unsigned int* __restrict__ maskp,
                         const float* __restrict__ s1g, const float* __restrict__ s2g,
                         const unsigned short* __restrict__ whT2,
                         float* __restrict__ out) {
  __shared__ float red[8][32][129];  // 132 KB (ks partials, f-half phased)
  __shared__ float lred[8][32];

  const int tid = threadIdx.x;
  const int lane = tid & 63;
  const int ksw = tid >> 6;  // 0..7 k-slice
  const int kbase = ksw * 1024;
  const int r16 = lane & 15;
  const int kg = lane >> 4;  // 8-k group within 32-k iter
  const int i0 = blockIdx.x * 32;
  const int row0 = i0 + r16;

  const unsigned int* mrow0 = maskp + (size_t)row0 * (NN / 32) + (kbase >> 5);
  const unsigned int* mrow1 = mrow0 + (size_t)16 * (NN / 32);
  const float* s2p = s2g + kbase + kg * 8;
  const unsigned short* bp = whT2 + (size_t)(kbase >> 5) * (FD * 32) + r16 * 32 + kg * 8;

  const float s1r0 = s1g[row0];
  const float s1r1 = s1g[row0 + 16];

  f32x4_t acc[2][16];
  const f32x4_t zero4 = {0.f, 0.f, 0.f, 0.f};
#pragma unroll
  for (int rt = 0; rt < 2; ++rt)
#pragma unroll
    for (int ct = 0; ct < 16; ++ct) acc[rt][ct] = zero4;

  float l0 = 0.f, l1 = 0.f;

  unsigned int cw0 = mrow0[0];
  unsigned int cw1 = mrow1[0];
  float4 csl = *(const float4*)(s2p);
  float4 csh = *(const float4*)(s2p + 4);

  for (int it = 0; it < 32; ++it) {
    const unsigned short* bk = bp + (size_t)it * (FD * 32);
    // group A: ct 0..7 (8 x 1KB contiguous wave-loads)
    bf16x8_t bA0 = *(const bf16x8_t*)(bk + 0 * 512);
    bf16x8_t bA1 = *(const bf16x8_t*)(bk + 1 * 512);
    bf16x8_t bA2 = *(const bf16x8_t*)(bk + 2 * 512);
    bf16x8_t bA3 = *(const bf16x8_t*)(bk + 3 * 512);
    bf16x8_t bA4 = *(const bf16x8_t*)(bk + 4 * 512);
    bf16x8_t bA5 = *(const bf16x8_t*)(bk + 5 * 512);
    bf16x8_t bA6 = *(const bf16x8_t*)(bk + 6 * 512);
    bf16x8_t bA7 = *(const bf16x8_t*)(bk + 7 * 512);

    // next iter's mask/s2
    const int itn = (it + 1 < 32) ? it + 1 : it;
    unsigned int nw0 = mrow0[itn];
    unsigned int nw1 = mrow1[itn];
    float4 nsl = *(const float4*)(s2p + itn * 32);
    float4 nsh = *(const float4*)(s2p + itn * 32 + 4);

    // P fragments (VALU covers group-A load latency)
    bf16x8_t af0 = make_afrag(s1r0, csl, csh, (cw0 >> (kg * 8)) & 0xffu, l0);
    bf16x8_t af1 = make_afrag(s1r1, csl, csh, (cw1 >> (kg * 8)) & 0xffu, l1);

    // group B loads issued before group-A MFMAs (latency under MFMA)
    bf16x8_t bB0 = *(const bf16x8_t*)(bk + 8 * 512);
    bf16x8_t bB1 = *(const bf16x8_t*)(bk + 9 * 512);
    bf16x8_t bB2 = *(const bf16x8_t*)(bk + 10 * 512);
    bf16x8_t bB3 = *(const bf16x8_t*)(bk + 11 * 512);
    bf16x8_t bB4 = *(const bf16x8_t*)(bk + 12 * 512);
    bf16x8_t bB5 = *(const bf16x8_t*)(bk + 13 * 512);
    bf16x8_t bB6 = *(const bf16x8_t*)(bk + 14 * 512);
    bf16x8_t bB7 = *(const bf16x8_t*)(bk + 15 * 512);

    acc[0][0] = __builtin_amdgcn_mfma_f32_16x16x32_bf16(af0, bA0, acc[0][0], 0, 0, 0);
    acc[1][0] = __builtin_amdgcn_mfma_f32_16x16x32_bf16(af1, bA0, acc[1][0], 0, 0, 0);
    acc[0][1] = __builtin_amdgcn_mfma_f32_16x16x32_bf16(af0, bA1, acc[0][1], 0, 0, 0);
    acc[1][1] = __builtin_amdgcn_mfma_f32_16x16x32_bf16(af1, bA1, acc[1][1], 0, 0, 0);
    acc[0][2] = __builtin_amdgcn_mfma_f32_16x16x32_bf16(af0, bA2, acc[0][2], 0, 0, 0);
    acc[1][2] = __builtin_amdgcn_mfma_f32_16x16x32_bf16(af1, bA2, acc[1][2], 0, 0, 0);
    acc[0][3] = __builtin_amdgcn_mfma_f32_16x16x32_bf16(af0, bA3, acc[0][3], 0, 0, 0);
    acc[1][3] = __builtin_amdgcn_mfma_f32_16x16x32_bf16(af1, bA3, acc[1][3], 0, 0, 0);
    acc[0][4] = __builtin_amdgcn_mfma_f32_16x16x32_bf16(af0, bA4, acc[0][4], 0, 0, 0);
    acc[1][4] = __builtin_amdgcn_mfma_f32_16x16x32_bf16(af1, bA4, acc[1][4], 0, 0, 0);
    acc[0][5] = __builtin_amdgcn_mfma_f32_16x16x32_bf16(af0, bA5, acc[0][5], 0, 0, 0);
    acc[1][5] = __builtin_amdgcn_mfma_f32_16x16x32_bf16(af1, bA5, acc[1][5], 0, 0, 0);
    acc[0][6] = __builtin_amdgcn_mfma_f32_16x16x32_bf16(af0, bA6, acc[0][6], 0, 0, 0);
    acc[1][6] = __builtin_amdgcn_mfma_f32_16x16x32_bf16(af1, bA6, acc[1][6], 0, 0, 0);
    acc[0][7] = __builtin_amdgcn_mfma_f32_16x16x32_bf16(af0, bA7, acc[0][7], 0, 0, 0);
    acc[1][7] = __builtin_amdgcn_mfma_f32_16x16x32_bf16(af1, bA7, acc[1][7], 0, 0, 0);

    acc[0][8] = __builtin_amdgcn_mfma_f32_16x16x32_bf16(af0, bB0, acc[0][8], 0, 0, 0);
    acc[1][8] = __builtin_amdgcn_mfma_f32_16x16x32_bf16(af1, bB0, acc[1][8], 0, 0, 0);
    acc[0][9] = __builtin_amdgcn_mfma_f32_16x16x32_bf16(af0, bB1, acc[0][9], 0, 0, 0);
    acc[1][9] = __builtin_amdgcn_mfma_f32_16x16x32_bf16(af1, bB1, acc[1][9], 0, 0, 0);
    acc[0][10] = __builtin_amdgcn_mfma_f32_16x16x32_bf16(af0, bB2, acc[0][10], 0, 0, 0);
    acc[1][10] = __builtin_amdgcn_mfma_f32_16x16x32_bf16(af1, bB2, acc[1][10], 0, 0, 0);
    acc[0][11] = __builtin_amdgcn_mfma_f32_16x16x32_bf16(af0, bB3, acc[0][11], 0, 0, 0);
    acc[1][11] = __builtin_amdgcn_mfma_f32_16x16x32_bf16(af1, bB3, acc[1][11], 0, 0, 0);
    acc[0][12] = __builtin_amdgcn_mfma_f32_16x16x32_bf16(af0, bB4, acc[0][12], 0, 0, 0);
    acc[1][12] = __builtin_amdgcn_mfma_f32_16x16x32_bf16(af1, bB4, acc[1][12], 0, 0, 0);
    acc[0][13] = __builtin_amdgcn_mfma_f32_16x16x32_bf16(af0, bB5, acc[0][13], 0, 0, 0);
    acc[1][13] = __builtin_amdgcn_mfma_f32_16x16x32_bf16(af1, bB5, acc[1][13], 0, 0, 0);
    acc[0][14] = __builtin_amdgcn_mfma_f32_16x16x32_bf16(af0, bB6, acc[0][14], 0, 0, 0);
    acc[1][14] = __builtin_amdgcn_mfma_f32_16x16x32_bf16(af1, bB6, acc[1][14], 0, 0, 0);
    acc[0][15] = __builtin_amdgcn_mfma_f32_16x16x32_bf16(af0, bB7, acc[0][15], 0, 0, 0);
    acc[1][15] = __builtin_amdgcn_mfma_f32_16x16x32_bf16(af1, bB7, acc[1][15], 0, 0, 0);

    cw0 = nw0; cw1 = nw1; csl = nsl; csh = nsh;
  }

  // ---- l: reduce over the 4 kg lane-groups of each row ----
  l0 += __shfl_xor(l0, 16, 64);
  l0 += __shfl_xor(l0, 32, 64);
  l1 += __shfl_xor(l1, 16, 64);
  l1 += __shfl_xor(l1, 32, 64);
  if (lane < 16) {
    lred[ksw][r16] = l0;
    lred[ksw][16 + r16] = l1;
  }

  // ---- 2-phase f-half reduction over 8 ks partials ----
#pragma unroll
  for (int ph = 0; ph < 2; ++ph) {
    if (ph) __syncthreads();  // WAR: phase-1 reads done before rewrite
#pragma unroll
    for (int rt = 0; rt < 2; ++rt) {
#pragma unroll
      for (int c = 0; c < 8; ++c) {
        const int ct = ph * 8 + c;
        const int col = c * 16 + r16;
#pragma unroll
        for (int g = 0; g < 4; ++g) {
          red[ksw][rt * 16 + kg * 4 + g][col] = acc[rt][ct][g];
        }
      }
    }
    __syncthreads();
    {
      const int row = tid >> 4;        // 0..31
      const int c8 = (tid & 15) * 8;   // 8 cols per thread
      const float lt = lred[0][row] + lred[1][row] + lred[2][row] + lred[3][row] +
                       lred[4][row] + lred[5][row] + lred[6][row] + lred[7][row];
      const float inv = 1.0f / lt;
      float ov[8];
#pragma unroll
      for (int c = 0; c < 8; ++c) {
        const int col = c8 + c;
        float s = red[0][row][col] + red[1][row][col] + red[2][row][col] +
                  red[3][row][col] + red[4][row][col] + red[5][row][col] +
                  red[6][row][col] + red[7][row][col];
        ov[c] = s * inv;
      }
      float* op = out + (size_t)(i0 + row) * FD + ph * 128 + c8;
      float4 o0 = {ov[0], ov[1], ov[2], ov[3]};
      float4 o1 = {ov[4], ov[5], ov[6], ov[7]};
      *(float4*)(op) = o0;
      *(float4*)(op + 4) = o1;
    }
  }
}

extern "C" void kernel_launch(void* const* d_in, const int* in_sizes, int n_in,
                              void* d_out, int out_size, void* d_ws, size_t ws_size,
                              hipStream_t stream) {
  const float* h = (const float*)d_in[0];
  const int* adj = (const int*)d_in[1];
  const float* W = (const float*)d_in[2];
  const float* a = (const float*)d_in[3];
  float* out = (float*)d_out;

  char* ws = (char*)d_ws;
  unsigned short* whT2 = (unsigned short*)ws;         // 4 MB (tiled layout)
  float* s1 = (float*)(ws + 4194304);                 // 32 KB
  float* s2 = (float*)(ws + 4194304 + 32768);         // 32 KB
  float* c1 = (float*)(ws + 4194304 + 65536);         // 1 KB
  float* c2 = (float*)(ws + 4194304 + 65536 + 1024);  // 1 KB
  unsigned long long* mask64 = (unsigned long long*)(ws + 5242880);  // 8 MB

  gat_pack<<<2048, 256, 0, stream>>>(adj, mask64);
  gat_cvec<<<1, 256, 0, stream>>>(W, a, c1, c2);
  gat_svec<<<NN / 4, 256, 0, stream>>>(h, c1, c2, s1, s2);
  gat_wht<<<dim3(NN / 64, FD / 64), 256, 0, stream>>>(h, W, whT2);
  gat_attn<<<NN / 32, 512, 0, stream>>>((const unsigned int*)mask64, s1, s2, whT2, out);
}

// Round 10
// 173.901 us; speedup vs baseline: 2.8294x; 1.0649x over previous
//
#include <hip/hip_runtime.h>
#include <hip/hip_bf16.h>
#include <stdint.h>

#define NN 8192
#define FD 256
#define SLOPE 0.2f
#define LOG2E 1.44269504088896f

typedef float f32x4_t __attribute__((ext_vector_type(4)));
typedef __bf16 bf16x8_t __attribute__((ext_vector_type(8)));
typedef unsigned short u16x8_t __attribute__((ext_vector_type(8)));

__device__ __forceinline__ unsigned short f2bf(float x) {
  unsigned int u = __builtin_bit_cast(unsigned int, x);
  u += 0x7FFFu + ((u >> 16) & 1u);  // RNE
  return (unsigned short)(u >> 16);
}

// ---------------- kernel 0: c1/c2[k] = sum_f W[f][k]*a{1,2}[f] ----------------
__global__ void gat_cvec(const float* __restrict__ W, const float* __restrict__ a,
                         float* __restrict__ c1, float* __restrict__ c2) {
  const int k = threadIdx.x;
  float acc1 = 0.f, acc2 = 0.f;
#pragma unroll 8
  for (int f = 0; f < FD; ++f) {
    float w = W[f * FD + k];
    acc1 = fmaf(w, a[f], acc1);
    acc2 = fmaf(w, a[FD + f], acc2);
  }
  c1[k] = acc1;
  c2[k] = acc2;
}

// ---- fused prep: blocks [0,512) wht | [512,2560) pack | [2560,4608) svec ----
// Independent workloads co-scheduled so pack's HBM stream overlaps wht's VALU.
__launch_bounds__(256)
__global__ void gat_prep(const float* __restrict__ h, const float* __restrict__ W,
                         const int* __restrict__ adj, const float* __restrict__ c1,
                         const float* __restrict__ c2,
                         unsigned short* __restrict__ whT2,
                         unsigned long long* __restrict__ mask64,
                         float* __restrict__ s1, float* __restrict__ s2) {
  __shared__ __align__(16) float hT[64][64];
  __shared__ __align__(16) float wT[64][64];
  const int b = blockIdx.x;
  const int t = threadIdx.x;

  if (b < 512) {
    // ---------------- wht: Wh = h @ W^T, tiled store whT2[i/32][f][i%32] ----
    const int i0 = (b & 127) * 64;
    const int f0 = (b >> 7) * 64;
    const int r = t & 63;
    const int kq = t >> 6;
    const int ty = t >> 4;
    const int tx = t & 15;
    float acc[4][4] = {};
    for (int k0 = 0; k0 < FD; k0 += 64) {
#pragma unroll
      for (int kk = 0; kk < 16; kk += 4) {
        float4 v = *(const float4*)(h + (size_t)(i0 + r) * FD + k0 + kq * 16 + kk);
        hT[kq * 16 + kk + 0][r] = v.x;
        hT[kq * 16 + kk + 1][r] = v.y;
        hT[kq * 16 + kk + 2][r] = v.z;
        hT[kq * 16 + kk + 3][r] = v.w;
        float4 u = *(const float4*)(W + (size_t)(f0 + r) * FD + k0 + kq * 16 + kk);
        wT[kq * 16 + kk + 0][r] = u.x;
        wT[kq * 16 + kk + 1][r] = u.y;
        wT[kq * 16 + kk + 2][r] = u.z;
        wT[kq * 16 + kk + 3][r] = u.w;
      }
      __syncthreads();
#pragma unroll 8
      for (int kk = 0; kk < 64; ++kk) {
        float4 av = *(const float4*)&hT[kk][ty * 4];
        float4 bv = *(const float4*)&wT[kk][tx * 4];
        acc[0][0] = fmaf(av.x, bv.x, acc[0][0]);
        acc[0][1] = fmaf(av.x, bv.y, acc[0][1]);
        acc[0][2] = fmaf(av.x, bv.z, acc[0][2]);
        acc[0][3] = fmaf(av.x, bv.w, acc[0][3]);
        acc[1][0] = fmaf(av.y, bv.x, acc[1][0]);
        acc[1][1] = fmaf(av.y, bv.y, acc[1][1]);
        acc[1][2] = fmaf(av.y, bv.z, acc[1][2]);
        acc[1][3] = fmaf(av.y, bv.w, acc[1][3]);
        acc[2][0] = fmaf(av.z, bv.x, acc[2][0]);
        acc[2][1] = fmaf(av.z, bv.y, acc[2][1]);
        acc[2][2] = fmaf(av.z, bv.z, acc[2][2]);
        acc[2][3] = fmaf(av.z, bv.w, acc[2][3]);
        acc[3][0] = fmaf(av.w, bv.x, acc[3][0]);
        acc[3][1] = fmaf(av.w, bv.y, acc[3][1]);
        acc[3][2] = fmaf(av.w, bv.z, acc[3][2]);
        acc[3][3] = fmaf(av.w, bv.w, acc[3][3]);
      }
      __syncthreads();
    }
    const int iv = i0 + ty * 4;
#pragma unroll
    for (int j = 0; j < 4; ++j) {
      const int f = f0 + tx * 4 + j;
      ushort4 o;
      o.x = f2bf(acc[0][j]);
      o.y = f2bf(acc[1][j]);
      o.z = f2bf(acc[2][j]);
      o.w = f2bf(acc[3][j]);
      *(ushort4*)(whT2 + (size_t)(iv >> 5) * (FD * 32) + (size_t)f * 32 + (iv & 31)) = o;
    }
  } else if (b < 2560) {
    // ---------------- pack: adj -> 64-bit ballot mask, coalesced ----
    const int vb = b - 512;  // 0..2047
    const int lane = t & 63;
    const int w = t >> 6;
    const size_t ngroups = (size_t)NN * NN / 256;
    const size_t nw = (size_t)2048 * 4;
    for (size_t g = (size_t)vb * 4 + w; g < ngroups; g += nw) {
      const int* p = adj + g * 256 + lane;
      int v0 = p[0];
      int v1 = p[64];
      int v2 = p[128];
      int v3 = p[192];
      unsigned long long m0 = __ballot(v0 != 0);
      unsigned long long m1 = __ballot(v1 != 0);
      unsigned long long m2 = __ballot(v2 != 0);
      unsigned long long m3 = __ballot(v3 != 0);
      if (lane < 4) {
        unsigned long long mv = lane == 0 ? m0 : lane == 1 ? m1 : lane == 2 ? m2 : m3;
        mask64[g * 4 + lane] = mv;
      }
    }
  } else {
    // ---------------- svec: s1/s2[i] = (h[i].c)*log2e ----
    const int i = (b - 2560) * 4 + (t >> 6);
    const int lane = t & 63;
    float4 hv = *(const float4*)(h + (size_t)i * FD + lane * 4);
    float4 u = *(const float4*)(c1 + lane * 4);
    float4 v = *(const float4*)(c2 + lane * 4);
    float d1 = hv.x * u.x + hv.y * u.y + hv.z * u.z + hv.w * u.w;
    float d2 = hv.x * v.x + hv.y * v.y + hv.z * v.z + hv.w * v.w;
#pragma unroll
    for (int m = 1; m < 64; m <<= 1) {
      d1 += __shfl_xor(d1, m, 64);
      d2 += __shfl_xor(d2, m, 64);
    }
    if (lane == 0) {
      s1[i] = d1 * LOG2E;
      s2[i] = d2 * LOG2E;
    }
  }
}

// ---- one MFMA A-fragment of P (8 cols) from an 8-bit mask; exp2 domain ------
__device__ __forceinline__ bf16x8_t make_afrag(float s1r, const float4& slo,
                                               const float4& shi, unsigned int mbyte,
                                               float& lsum) {
  const float sv[8] = {slo.x, slo.y, slo.z, slo.w, shi.x, shi.y, shi.z, shi.w};
  u16x8_t ru;
#pragma unroll
  for (int c = 0; c < 8; ++c) {
    float x = s1r + sv[c];    // already log2e-scaled
    x = fmaxf(x, SLOPE * x);  // leaky commutes with positive scale
    float pv = exp2f(x);      // v_exp_f32
    pv = ((mbyte >> c) & 1u) ? pv : 0.f;
    lsum += pv;
    ru[c] = f2bf(pv);
  }
  return __builtin_bit_cast(bf16x8_t, ru);
}

// ---------------- attention: sched_barrier-pinned load/VALU/MFMA phases ------
// grid 256 x 512 thr (1 block/CU, LDS 133 KB). Block = 32 rows; 8 waves = 8
// k-slices of 1024. Wave = 32 rows x 256 f x 1024 k; B-frags contiguous from
// tiled whT2 (1 KB/load). Per iter: [16 B + mask + s2 loads] SBAR [afrag VALU]
// SBAR [64 MFMA] -- fences stop the compiler sinking loads to uses (the
// r5/r6/r9 latency-serialization failure). Live set ~230 < 256 cap: no spill.
__launch_bounds__(512, 2)
__global__ void gat_attn(const unsigned int* __restrict__ maskp,
                         const float* __restrict__ s1g, const float* __restrict__ s2g,
                         const unsigned short* __restrict__ whT2,
                         float* __restrict__ out) {
  __shared__ float red[8][32][129];  // 132 KB
  __shared__ float lred[8][32];

  const int tid = threadIdx.x;
  const int lane = tid & 63;
  const int ksw = tid >> 6;  // 0..7 k-slice
  const int kbase = ksw * 1024;
  const int r16 = lane & 15;
  const int kg = lane >> 4;
  const int i0 = blockIdx.x * 32;
  const int row0 = i0 + r16;

  const unsigned int* mrow0 = maskp + (size_t)row0 * (NN / 32) + (kbase >> 5);
  const unsigned int* mrow1 = mrow0 + (size_t)16 * (NN / 32);
  const float* s2p = s2g + kbase + kg * 8;
  const unsigned short* bp = whT2 + (size_t)(kbase >> 5) * (FD * 32) + r16 * 32 + kg * 8;

  const float s1r0 = s1g[row0];
  const float s1r1 = s1g[row0 + 16];

  f32x4_t acc[2][16];
  const f32x4_t zero4 = {0.f, 0.f, 0.f, 0.f};
#pragma unroll
  for (int rt = 0; rt < 2; ++rt)
#pragma unroll
    for (int ct = 0; ct < 16; ++ct) acc[rt][ct] = zero4;

  float l0 = 0.f, l1 = 0.f;

  unsigned int cw0 = mrow0[0];
  unsigned int cw1 = mrow1[0];
  float4 csl = *(const float4*)(s2p);
  float4 csh = *(const float4*)(s2p + 4);

  for (int it = 0; it < 32; ++it) {
    const unsigned short* bk = bp + (size_t)it * (FD * 32);
    // ---- phase L: ALL vmem issues for this iter ----
    bf16x8_t bA0 = *(const bf16x8_t*)(bk + 0 * 512);
    bf16x8_t bA1 = *(const bf16x8_t*)(bk + 1 * 512);
    bf16x8_t bA2 = *(const bf16x8_t*)(bk + 2 * 512);
    bf16x8_t bA3 = *(const bf16x8_t*)(bk + 3 * 512);
    bf16x8_t bA4 = *(const bf16x8_t*)(bk + 4 * 512);
    bf16x8_t bA5 = *(const bf16x8_t*)(bk + 5 * 512);
    bf16x8_t bA6 = *(const bf16x8_t*)(bk + 6 * 512);
    bf16x8_t bA7 = *(const bf16x8_t*)(bk + 7 * 512);
    bf16x8_t bB0 = *(const bf16x8_t*)(bk + 8 * 512);
    bf16x8_t bB1 = *(const bf16x8_t*)(bk + 9 * 512);
    bf16x8_t bB2 = *(const bf16x8_t*)(bk + 10 * 512);
    bf16x8_t bB3 = *(const bf16x8_t*)(bk + 11 * 512);
    bf16x8_t bB4 = *(const bf16x8_t*)(bk + 12 * 512);
    bf16x8_t bB5 = *(const bf16x8_t*)(bk + 13 * 512);
    bf16x8_t bB6 = *(const bf16x8_t*)(bk + 14 * 512);
    bf16x8_t bB7 = *(const bf16x8_t*)(bk + 15 * 512);
    const int itn = (it + 1 < 32) ? it + 1 : it;
    unsigned int nw0 = mrow0[itn];
    unsigned int nw1 = mrow1[itn];
    float4 nsl = *(const float4*)(s2p + itn * 32);
    float4 nsh = *(const float4*)(s2p + itn * 32 + 4);
    __builtin_amdgcn_sched_barrier(0);

    // ---- phase V: P fragments from PREVIOUS iter's regs (no mem wait) ----
    bf16x8_t af0 = make_afrag(s1r0, csl, csh, (cw0 >> (kg * 8)) & 0xffu, l0);
    bf16x8_t af1 = make_afrag(s1r1, csl, csh, (cw1 >> (kg * 8)) & 0xffu, l1);
    __builtin_amdgcn_sched_barrier(0);

    // ---- phase M: 64 MFMAs ----
    acc[0][0] = __builtin_amdgcn_mfma_f32_16x16x32_bf16(af0, bA0, acc[0][0], 0, 0, 0);
    acc[1][0] = __builtin_amdgcn_mfma_f32_16x16x32_bf16(af1, bA0, acc[1][0], 0, 0, 0);
    acc[0][1] = __builtin_amdgcn_mfma_f32_16x16x32_bf16(af0, bA1, acc[0][1], 0, 0, 0);
    acc[1][1] = __builtin_amdgcn_mfma_f32_16x16x32_bf16(af1, bA1, acc[1][1], 0, 0, 0);
    acc[0][2] = __builtin_amdgcn_mfma_f32_16x16x32_bf16(af0, bA2, acc[0][2], 0, 0, 0);
    acc[1][2] = __builtin_amdgcn_mfma_f32_16x16x32_bf16(af1, bA2, acc[1][2], 0, 0, 0);
    acc[0][3] = __builtin_amdgcn_mfma_f32_16x16x32_bf16(af0, bA3, acc[0][3], 0, 0, 0);
    acc[1][3] = __builtin_amdgcn_mfma_f32_16x16x32_bf16(af1, bA3, acc[1][3], 0, 0, 0);
    acc[0][4] = __builtin_amdgcn_mfma_f32_16x16x32_bf16(af0, bA4, acc[0][4], 0, 0, 0);
    acc[1][4] = __builtin_amdgcn_mfma_f32_16x16x32_bf16(af1, bA4, acc[1][4], 0, 0, 0);
    acc[0][5] = __builtin_amdgcn_mfma_f32_16x16x32_bf16(af0, bA5, acc[0][5], 0, 0, 0);
    acc[1][5] = __builtin_amdgcn_mfma_f32_16x16x32_bf16(af1, bA5, acc[1][5], 0, 0, 0);
    acc[0][6] = __builtin_amdgcn_mfma_f32_16x16x32_bf16(af0, bA6, acc[0][6], 0, 0, 0);
    acc[1][6] = __builtin_amdgcn_mfma_f32_16x16x32_bf16(af1, bA6, acc[1][6], 0, 0, 0);
    acc[0][7] = __builtin_amdgcn_mfma_f32_16x16x32_bf16(af0, bA7, acc[0][7], 0, 0, 0);
    acc[1][7] = __builtin_amdgcn_mfma_f32_16x16x32_bf16(af1, bA7, acc[1][7], 0, 0, 0);
    acc[0][8] = __builtin_amdgcn_mfma_f32_16x16x32_bf16(af0, bB0, acc[0][8], 0, 0, 0);
    acc[1][8] = __builtin_amdgcn_mfma_f32_16x16x32_bf16(af1, bB0, acc[1][8], 0, 0, 0);
    acc[0][9] = __builtin_amdgcn_mfma_f32_16x16x32_bf16(af0, bB1, acc[0][9], 0, 0, 0);
    acc[1][9] = __builtin_amdgcn_mfma_f32_16x16x32_bf16(af1, bB1, acc[1][9], 0, 0, 0);
    acc[0][10] = __builtin_amdgcn_mfma_f32_16x16x32_bf16(af0, bB2, acc[0][10], 0, 0, 0);
    acc[1][10] = __builtin_amdgcn_mfma_f32_16x16x32_bf16(af1, bB2, acc[1][10], 0, 0, 0);
    acc[0][11] = __builtin_amdgcn_mfma_f32_16x16x32_bf16(af0, bB3, acc[0][11], 0, 0, 0);
    acc[1][11] = __builtin_amdgcn_mfma_f32_16x16x32_bf16(af1, bB3, acc[1][11], 0, 0, 0);
    acc[0][12] = __builtin_amdgcn_mfma_f32_16x16x32_bf16(af0, bB4, acc[0][12], 0, 0, 0);
    acc[1][12] = __builtin_amdgcn_mfma_f32_16x16x32_bf16(af1, bB4, acc[1][12], 0, 0, 0);
    acc[0][13] = __builtin_amdgcn_mfma_f32_16x16x32_bf16(af0, bB5, acc[0][13], 0, 0, 0);
    acc[1][13] = __builtin_amdgcn_mfma_f32_16x16x32_bf16(af1, bB5, acc[1][13], 0, 0, 0);
    acc[0][14] = __builtin_amdgcn_mfma_f32_16x16x32_bf16(af0, bB6, acc[0][14], 0, 0, 0);
    acc[1][14] = __builtin_amdgcn_mfma_f32_16x16x32_bf16(af1, bB6, acc[1][14], 0, 0, 0);
    acc[0][15] = __builtin_amdgcn_mfma_f32_16x16x32_bf16(af0, bB7, acc[0][15], 0, 0, 0);
    acc[1][15] = __builtin_amdgcn_mfma_f32_16x16x32_bf16(af1, bB7, acc[1][15], 0, 0, 0);

    cw0 = nw0; cw1 = nw1; csl = nsl; csh = nsh;
  }

  // ---- l: reduce over the 4 kg lane-groups of each row ----
  l0 += __shfl_xor(l0, 16, 64);
  l0 += __shfl_xor(l0, 32, 64);
  l1 += __shfl_xor(l1, 16, 64);
  l1 += __shfl_xor(l1, 32, 64);
  if (lane < 16) {
    lred[ksw][r16] = l0;
    lred[ksw][16 + r16] = l1;
  }

  // ---- 2-phase f-half reduction over 8 ks partials ----
#pragma unroll
  for (int ph = 0; ph < 2; ++ph) {
    if (ph) __syncthreads();  // WAR: phase-0 reads done before rewrite
#pragma unroll
    for (int rt = 0; rt < 2; ++rt) {
#pragma unroll
      for (int c = 0; c < 8; ++c) {
        const int ct = ph * 8 + c;
        const int col = c * 16 + r16;
#pragma unroll
        for (int g = 0; g < 4; ++g) {
          red[ksw][rt * 16 + kg * 4 + g][col] = acc[rt][ct][g];
        }
      }
    }
    __syncthreads();
    {
      const int row = tid >> 4;       // 0..31
      const int c8 = (tid & 15) * 8;  // 8 cols per thread
      const float lt = lred[0][row] + lred[1][row] + lred[2][row] + lred[3][row] +
                       lred[4][row] + lred[5][row] + lred[6][row] + lred[7][row];
      const float inv = 1.0f / lt;
      float ov[8];
#pragma unroll
      for (int c = 0; c < 8; ++c) {
        const int col = c8 + c;
        float s = red[0][row][col] + red[1][row][col] + red[2][row][col] +
                  red[3][row][col] + red[4][row][col] + red[5][row][col] +
                  red[6][row][col] + red[7][row][col];
        ov[c] = s * inv;
      }
      float* op = out + (size_t)(i0 + row) * FD + ph * 128 + c8;
      float4 o0 = {ov[0], ov[1], ov[2], ov[3]};
      float4 o1 = {ov[4], ov[5], ov[6], ov[7]};
      *(float4*)(op) = o0;
      *(float4*)(op + 4) = o1;
    }
  }
}

extern "C" void kernel_launch(void* const* d_in, const int* in_sizes, int n_in,
                              void* d_out, int out_size, void* d_ws, size_t ws_size,
                              hipStream_t stream) {
  const float* h = (const float*)d_in[0];
  const int* adj = (const int*)d_in[1];
  const float* W = (const float*)d_in[2];
  const float* a = (const float*)d_in[3];
  float* out = (float*)d_out;

  char* ws = (char*)d_ws;
  unsigned short* whT2 = (unsigned short*)ws;         // 4 MB (tiled layout)
  float* s1 = (float*)(ws + 4194304);                 // 32 KB
  float* s2 = (float*)(ws + 4194304 + 32768);         // 32 KB
  float* c1 = (float*)(ws + 4194304 + 65536);         // 1 KB
  float* c2 = (float*)(ws + 4194304 + 65536 + 1024);  // 1 KB
  unsigned long long* mask64 = (unsigned long long*)(ws + 5242880);  // 8 MB

  gat_cvec<<<1, 256, 0, stream>>>(W, a, c1, c2);
  gat_prep<<<4608, 256, 0, stream>>>(h, W, adj, c1, c2, whT2, mask64, s1, s2);
  gat_attn<<<NN / 32, 512, 0, stream>>>((const unsigned int*)mask64, s1, s2, whT2, out);
}